// Round 2
// baseline (381.789 us; speedup 1.0000x reference)
//
#include <hip/hip_runtime.h>
#include <hip/hip_bf16.h>
#include <math.h>

#define BB 16
#define SS 2048
#define DD 512
#define MM 256
#define RR 64
#define KK 16

__device__ __forceinline__ float wave_sum(float v) {
#pragma unroll
  for (int off = 32; off > 0; off >>= 1) v += __shfl_xor(v, off);
  return v;
}

__device__ __forceinline__ float sgnf(float v) {
  return (v > 0.f) ? 1.f : ((v < 0.f) ? -1.f : 0.f);
}

// butterfly argmax over 64 lanes carrying (abs, idx, signed val); ties -> smaller idx
__device__ __forceinline__ void wave_argmax(float& a, int& j, float& v) {
#pragma unroll
  for (int off = 32; off > 0; off >>= 1) {
    float oa = __shfl_xor(a, off);
    int oj = __shfl_xor(j, off);
    float ov = __shfl_xor(v, off);
    if (oa > a || (oa == a && oj < j)) { a = oa; j = oj; v = ov; }
  }
}

// ---------------------------------------------------------------------------
// LN(init_val) -> mv0 [M,D]; pt0[m,r] = (mv0[m]·rUt_w[:,r] + rUt_b[r])*r_w[r]*0.1
// ---------------------------------------------------------------------------
__global__ __launch_bounds__(256) void k_init(
    const float* __restrict__ init_val, const float* __restrict__ ln_g,
    const float* __restrict__ ln_b, const float* __restrict__ rUt_w,
    const float* __restrict__ rUt_b, const float* __restrict__ r_w,
    float* __restrict__ mv0, float* __restrict__ pt0) {
  int m = blockIdx.x, t = threadIdx.x;
  __shared__ float row[DD];
  __shared__ float red[8];
  float x0 = init_val[m * DD + t];
  float x1 = init_val[m * DD + t + 256];
  float s = wave_sum(x0 + x1);
  float sq = wave_sum(x0 * x0 + x1 * x1);
  if ((t & 63) == 0) { red[t >> 6] = s; red[4 + (t >> 6)] = sq; }
  __syncthreads();
  float mean = (red[0] + red[1] + red[2] + red[3]) * (1.0f / DD);
  float var = (red[4] + red[5] + red[6] + red[7]) * (1.0f / DD) - mean * mean;
  float rs = rsqrtf(var + 1e-5f);
  float n0 = (x0 - mean) * rs * ln_g[t] + ln_b[t];
  float n1 = (x1 - mean) * rs * ln_g[t + 256] + ln_b[t + 256];
  mv0[m * DD + t] = n0;
  mv0[m * DD + t + 256] = n1;
  row[t] = n0;
  row[t + 256] = n1;
  __syncthreads();
  if (t < RR) {
    float acc = rUt_b[t];
    for (int d = 0; d < DD; ++d) acc += row[d] * rUt_w[d * RR + t];
    pt0[m * RR + t] = acc * r_w[t] * 0.1f;
  }
}

// ---------------------------------------------------------------------------
// signed_softmax_state over 256 elements per block-row: out = sign*softmax(|x|)*4
// ---------------------------------------------------------------------------
__global__ __launch_bounds__(256) void k_state_softmax(
    const float* __restrict__ in, float* __restrict__ out) {
  int b = blockIdx.x, t = threadIdx.x;
  __shared__ float red[4];
  float v = in[b * MM + t];
  float a = fabsf(v);
  float mx = a;
#pragma unroll
  for (int off = 32; off > 0; off >>= 1) mx = fmaxf(mx, __shfl_xor(mx, off));
  if ((t & 63) == 0) red[t >> 6] = mx;
  __syncthreads();
  mx = fmaxf(fmaxf(red[0], red[1]), fmaxf(red[2], red[3]));
  __syncthreads();
  float e = expf(a - mx);
  float ssum = wave_sum(e);
  if ((t & 63) == 0) red[t >> 6] = ssum;
  __syncthreads();
  ssum = red[0] + red[1] + red[2] + red[3];
  out[b * MM + t] = sgnf(v) * e / ssum * 4.0f;
}

// ---------------------------------------------------------------------------
// C[rows,64] = A[rows,512] @ W[512,64] + bias; optional colscale*(csmul),
// optional rowscale; optional transposed per-batch output [B,64,256].
// ---------------------------------------------------------------------------
template <bool TRANS_OUT>
__global__ __launch_bounds__(256) void k_gemm512x64(
    const float* __restrict__ A, const float* __restrict__ W,
    const float* __restrict__ bias, const float* __restrict__ colscale,
    float csmul, const float* __restrict__ rowscale, float* __restrict__ C) {
  __shared__ float As[64][65];
  __shared__ float Ws[64][65];
  int tid = threadIdx.x;
  int ty = tid >> 4, tx = tid & 15;
  int row0 = blockIdx.x * 64;
  float acc[4][4] = {};
  for (int kc = 0; kc < DD; kc += 64) {
#pragma unroll
    for (int i = 0; i < 4; ++i) {
      int idx4 = i * 256 + tid;
      int r = idx4 >> 4;
      int c = (idx4 & 15) << 2;
      float4 va = *reinterpret_cast<const float4*>(
          &A[(size_t)(row0 + r) * DD + kc + c]);
      As[r][c] = va.x; As[r][c + 1] = va.y; As[r][c + 2] = va.z; As[r][c + 3] = va.w;
      float4 vw = *reinterpret_cast<const float4*>(&W[(size_t)(kc + r) * RR + c]);
      Ws[r][c] = vw.x; Ws[r][c + 1] = vw.y; Ws[r][c + 2] = vw.z; Ws[r][c + 3] = vw.w;
    }
    __syncthreads();
#pragma unroll
    for (int k = 0; k < 64; ++k) {
      float a0 = As[ty * 4 + 0][k], a1 = As[ty * 4 + 1][k];
      float a2 = As[ty * 4 + 2][k], a3 = As[ty * 4 + 3][k];
      float b0 = Ws[k][tx * 4 + 0], b1 = Ws[k][tx * 4 + 1];
      float b2 = Ws[k][tx * 4 + 2], b3 = Ws[k][tx * 4 + 3];
      acc[0][0] += a0 * b0; acc[0][1] += a0 * b1; acc[0][2] += a0 * b2; acc[0][3] += a0 * b3;
      acc[1][0] += a1 * b0; acc[1][1] += a1 * b1; acc[1][2] += a1 * b2; acc[1][3] += a1 * b3;
      acc[2][0] += a2 * b0; acc[2][1] += a2 * b1; acc[2][2] += a2 * b2; acc[2][3] += a2 * b3;
      acc[3][0] += a3 * b0; acc[3][1] += a3 * b1; acc[3][2] += a3 * b2; acc[3][3] += a3 * b3;
    }
    __syncthreads();
  }
#pragma unroll
  for (int i = 0; i < 4; ++i) {
    int rr = row0 + ty * 4 + i;
#pragma unroll
    for (int j = 0; j < 4; ++j) {
      int cc = tx * 4 + j;
      float v = acc[i][j] + bias[cc];
      if (colscale) v *= colscale[cc] * csmul;
      if (rowscale) v *= rowscale[rr];
      if (TRANS_OUT) {
        int b = rr >> 8;
        int mm = rr & 255;
        C[((size_t)b * RR + cc) * MM + mm] = v;
      } else {
        C[(size_t)rr * RR + cc] = v;
      }
    }
  }
}

// ---------------------------------------------------------------------------
// scores[b,m,j] = pt0[m,:]·ps[b,j,:]   (K=64). Tile 64m x 64j.
// ---------------------------------------------------------------------------
__global__ __launch_bounds__(256) void k_scores(
    const float* __restrict__ pt0, const float* __restrict__ ps,
    float* __restrict__ scores) {
  int b = blockIdx.z;
  int m0 = blockIdx.y * 64;
  int j0 = blockIdx.x * 64;
  __shared__ float Pt[64][65];
  __shared__ float Ps[64][65];
  int tid = threadIdx.x;
  int ty = tid >> 4, tx = tid & 15;
#pragma unroll
  for (int i = 0; i < 4; ++i) {
    int idx4 = i * 256 + tid;
    int r = idx4 >> 4;
    int c = (idx4 & 15) << 2;
    float4 vp = *reinterpret_cast<const float4*>(&pt0[(size_t)(m0 + r) * RR + c]);
    Pt[r][c] = vp.x; Pt[r][c + 1] = vp.y; Pt[r][c + 2] = vp.z; Pt[r][c + 3] = vp.w;
    float4 vs = *reinterpret_cast<const float4*>(
        &ps[((size_t)b * SS + j0 + r) * RR + c]);
    Ps[r][c] = vs.x; Ps[r][c + 1] = vs.y; Ps[r][c + 2] = vs.z; Ps[r][c + 3] = vs.w;
  }
  __syncthreads();
  float acc[4][4] = {};
#pragma unroll
  for (int k = 0; k < 64; ++k) {
    float a0 = Pt[ty * 4 + 0][k], a1 = Pt[ty * 4 + 1][k];
    float a2 = Pt[ty * 4 + 2][k], a3 = Pt[ty * 4 + 3][k];
    float b0 = Ps[tx * 4 + 0][k], b1 = Ps[tx * 4 + 1][k];
    float b2 = Ps[tx * 4 + 2][k], b3 = Ps[tx * 4 + 3][k];
    acc[0][0] += a0 * b0; acc[0][1] += a0 * b1; acc[0][2] += a0 * b2; acc[0][3] += a0 * b3;
    acc[1][0] += a1 * b0; acc[1][1] += a1 * b1; acc[1][2] += a1 * b2; acc[1][3] += a1 * b3;
    acc[2][0] += a2 * b0; acc[2][1] += a2 * b1; acc[2][2] += a2 * b2; acc[2][3] += a2 * b3;
    acc[3][0] += a3 * b0; acc[3][1] += a3 * b1; acc[3][2] += a3 * b2; acc[3][3] += a3 * b3;
  }
  float* obase = scores + (size_t)b * MM * SS;
#pragma unroll
  for (int i = 0; i < 4; ++i) {
#pragma unroll
    for (int j = 0; j < 4; ++j) {
      obase[(size_t)(m0 + ty * 4 + i) * SS + j0 + tx * 4 + j] = acc[i][j];
    }
  }
}

// ---------------------------------------------------------------------------
// Per (b,m): wave-parallel top-16 of |scores row| (barrier-free per wave,
// one block barrier total) -> signed-abs-softmax -> gather -> LN -> mv1.
// ---------------------------------------------------------------------------
__global__ __launch_bounds__(256) void k_write(
    const float* __restrict__ scores, const float* __restrict__ token_val,
    const float* __restrict__ token_state, const float* __restrict__ mv0,
    const float* __restrict__ ms0, const float* __restrict__ ln_g,
    const float* __restrict__ ln_b, float* __restrict__ mv1,
    float* __restrict__ ms_w) {
  int m = blockIdx.x, b = blockIdx.y, t = threadIdx.x;
  int wave = t >> 6, lane = t & 63;
  __shared__ float candv[64];
  __shared__ int candj[64];
  __shared__ float red[8];
  const float* srow = scores + ((size_t)b * MM + m) * SS;
  int jbase = wave * 512 + lane * 8;
  float4 q0 = *reinterpret_cast<const float4*>(srow + jbase);
  float4 q1 = *reinterpret_cast<const float4*>(srow + jbase + 4);
  float sc[8] = {q0.x, q0.y, q0.z, q0.w, q1.x, q1.y, q1.z, q1.w};
  float av[8];
#pragma unroll
  for (int c = 0; c < 8; ++c) av[c] = fabsf(sc[c]);
  // wave-local top-16 of this wave's 512 scores (no barriers)
#pragma unroll
  for (int it = 0; it < KK; ++it) {
    float lv = av[0]; float lsv = sc[0]; int lj = jbase;
#pragma unroll
    for (int c = 1; c < 8; ++c)
      if (av[c] > lv) { lv = av[c]; lsv = sc[c]; lj = jbase + c; }
    wave_argmax(lv, lj, lsv);
    if (lane == it) { candv[wave * KK + it] = lsv; candj[wave * KK + it] = lj; }
    if (((lj >> 3) & 63) == lane) {
#pragma unroll
      for (int c = 0; c < 8; ++c)
        if ((lj & 7) == c) av[c] = -1.f;
    }
  }
  __syncthreads();
  // merge 4x16 candidates -> top-16, redundantly in every wave (no broadcast)
  float cv = candv[lane]; int cj = candj[lane]; float ca = fabsf(cv);
  float selv[KK]; int selj[KK];
#pragma unroll
  for (int it = 0; it < KK; ++it) {
    float a2 = ca; int j2 = cj; float v2 = cv;
    wave_argmax(a2, j2, v2);
    selv[it] = v2; selj[it] = j2;
    if (cj == j2) ca = -1.f;
  }
  // signed-abs-softmax over the 16 selected (in registers)
  float mx = 0.f;
#pragma unroll
  for (int k = 0; k < KK; ++k) mx = fmaxf(mx, fabsf(selv[k]));
  float es[KK]; float ssum = 0.f;
#pragma unroll
  for (int k = 0; k < KK; ++k) {
    float ex = expf(fabsf(selv[k]) - mx);
    ssum += ex;
    es[k] = sgnf(selv[k]) * ex;
  }
  float inv = 1.f / ssum;
  float acc0 = mv0[m * DD + t];
  float acc1 = mv0[m * DD + t + 256];
  float stacc = 0.f;
#pragma unroll
  for (int k = 0; k < KK; ++k) {
    int j = selj[k];
    float e = es[k] * inv;
    const float* tv = token_val + ((size_t)b * SS + j) * DD;
    acc0 += e * tv[t];
    acc1 += e * tv[t + 256];
    stacc += e * token_state[b * SS + j];
  }
  if (t == 0) ms_w[b * MM + m] = ms0[m] + stacc;
  float s = wave_sum(acc0 + acc1);
  float sq = wave_sum(acc0 * acc0 + acc1 * acc1);
  if ((t & 63) == 0) { red[t >> 6] = s; red[4 + (t >> 6)] = sq; }
  __syncthreads();
  float mean = (red[0] + red[1] + red[2] + red[3]) * (1.0f / DD);
  float var = (red[4] + red[5] + red[6] + red[7]) * (1.0f / DD) - mean * mean;
  float rs = rsqrtf(var + 1e-5f);
  float* orow = mv1 + ((size_t)b * MM + m) * DD;
  orow[t] = (acc0 - mean) * rs * ln_g[t] + ln_b[t];
  orow[t + 256] = (acc1 - mean) * rs * ln_g[t + 256] + ln_b[t + 256];
}

// ---------------------------------------------------------------------------
// Per (b,m): pscores[j] = pt1[b,m,:]·ps1T[b,:,j] (ms1 folded into ps1T);
// wave-parallel top-16 -> edges -> gather mv1 -> residual -> LN -> out.
// ---------------------------------------------------------------------------
__global__ __launch_bounds__(256) void k_prop(
    const float* __restrict__ pt1, const float* __restrict__ ps1T,
    const float* __restrict__ mv1, const float* __restrict__ ln_g,
    const float* __restrict__ ln_b, float* __restrict__ out) {
  int m = blockIdx.x, b = blockIdx.y, t = threadIdx.x;
  int wave = t >> 6, lane = t & 63;
  __shared__ float ptrow[RR];
  __shared__ float candv[64];
  __shared__ int candj[64];
  __shared__ float red[8];
  if (t < RR) ptrow[t] = pt1[((size_t)b * MM + m) * RR + t];
  __syncthreads();
  const float* pB = ps1T + (size_t)b * RR * MM;
  float sc = 0.f;
#pragma unroll 8
  for (int r = 0; r < RR; ++r) sc += ptrow[r] * pB[r * MM + t];
  // wave-local top-16 of this wave's 64 scores (j = t, one per lane)
  float ca0 = fabsf(sc); int cj0 = t; float cv0 = sc;
#pragma unroll
  for (int it = 0; it < KK; ++it) {
    float a2 = ca0; int j2 = cj0; float v2 = cv0;
    wave_argmax(a2, j2, v2);
    if (lane == it) { candv[wave * KK + it] = v2; candj[wave * KK + it] = j2; }
    if (cj0 == j2) ca0 = -1.f;
  }
  __syncthreads();
  float cv = candv[lane]; int cj = candj[lane]; float ca = fabsf(cv);
  float selv[KK]; int selj[KK];
#pragma unroll
  for (int it = 0; it < KK; ++it) {
    float a2 = ca; int j2 = cj; float v2 = cv;
    wave_argmax(a2, j2, v2);
    selv[it] = v2; selj[it] = j2;
    if (cj == j2) ca = -1.f;
  }
  float mx = 0.f;
#pragma unroll
  for (int k = 0; k < KK; ++k) mx = fmaxf(mx, fabsf(selv[k]));
  float es[KK]; float ssum = 0.f;
#pragma unroll
  for (int k = 0; k < KK; ++k) {
    float ex = expf(fabsf(selv[k]) - mx);
    ssum += ex;
    es[k] = sgnf(selv[k]) * ex;
  }
  float inv = 1.f / ssum;
  const float* mrow = mv1 + ((size_t)b * MM + m) * DD;
  float acc0 = mrow[t];
  float acc1 = mrow[t + 256];
#pragma unroll
  for (int k = 0; k < KK; ++k) {
    int j = selj[k];
    float e = es[k] * inv;
    const float* pv = mv1 + ((size_t)b * MM + j) * DD;
    acc0 += e * pv[t];
    acc1 += e * pv[t + 256];
  }
  float s = wave_sum(acc0 + acc1);
  float sq = wave_sum(acc0 * acc0 + acc1 * acc1);
  if ((t & 63) == 0) { red[t >> 6] = s; red[4 + (t >> 6)] = sq; }
  __syncthreads();
  float mean = (red[0] + red[1] + red[2] + red[3]) * (1.0f / DD);
  float var = (red[4] + red[5] + red[6] + red[7]) * (1.0f / DD) - mean * mean;
  float rs = rsqrtf(var + 1e-5f);
  float* orow = out + ((size_t)b * MM + m) * DD;
  orow[t] = (acc0 - mean) * rs * ln_g[t] + ln_b[t];
  orow[t + 256] = (acc1 - mean) * rs * ln_g[t + 256] + ln_b[t + 256];
}

extern "C" void kernel_launch(void* const* d_in, const int* in_sizes, int n_in,
                              void* d_out, int out_size, void* d_ws,
                              size_t ws_size, hipStream_t stream) {
  const float* token_val = (const float*)d_in[0];
  const float* token_state = (const float*)d_in[1];
  const float* init_state = (const float*)d_in[2];
  const float* init_val = (const float*)d_in[3];
  const float* rUs_w = (const float*)d_in[4];
  const float* rUs_b = (const float*)d_in[5];
  const float* rUt_w = (const float*)d_in[6];
  const float* rUt_b = (const float*)d_in[7];
  const float* r_w = (const float*)d_in[8];
  const float* pUs_w = (const float*)d_in[9];
  const float* pUs_b = (const float*)d_in[10];
  const float* pUt_w = (const float*)d_in[11];
  const float* pUt_b = (const float*)d_in[12];
  const float* p_w = (const float*)d_in[13];
  const float* ln_g = (const float*)d_in[14];
  const float* ln_b = (const float*)d_in[15];
  float* out = (float*)d_out;

  float* ws = (float*)d_ws;
  float* mv0 = ws;    ws += MM * DD;
  float* pt0 = ws;    ws += MM * RR;
  float* ms0 = ws;    ws += MM;
  float* ps = ws;     ws += (size_t)BB * SS * RR;
  float* scores = ws; ws += (size_t)BB * MM * SS;
  float* mv1 = ws;    ws += (size_t)BB * MM * DD;
  float* ms_w = ws;   ws += BB * MM;
  float* ms1 = ws;    ws += BB * MM;
  float* pt1 = ws;    ws += (size_t)BB * MM * RR;
  float* ps1T = ws;   ws += (size_t)BB * RR * MM;

  k_init<<<MM, 256, 0, stream>>>(init_val, ln_g, ln_b, rUt_w, rUt_b, r_w, mv0, pt0);
  k_state_softmax<<<1, 256, 0, stream>>>(init_state, ms0);
  k_gemm512x64<false><<<(BB * SS) / 64, 256, 0, stream>>>(
      token_val, rUs_w, rUs_b, nullptr, 1.f, nullptr, ps);
  dim3 gs(SS / 64, MM / 64, BB);
  k_scores<<<gs, 256, 0, stream>>>(pt0, ps, scores);
  dim3 gw(MM, BB);
  k_write<<<gw, 256, 0, stream>>>(scores, token_val, token_state, mv0, ms0,
                                  ln_g, ln_b, mv1, ms_w);
  k_state_softmax<<<BB, 256, 0, stream>>>(ms_w, ms1);
  k_gemm512x64<false><<<(BB * MM) / 64, 256, 0, stream>>>(
      mv1, pUt_w, pUt_b, p_w, 0.1f, nullptr, pt1);
  k_gemm512x64<true><<<(BB * MM) / 64, 256, 0, stream>>>(
      mv1, pUs_w, pUs_b, nullptr, 1.f, ms1, ps1T);
  k_prop<<<gw, 256, 0, stream>>>(pt1, ps1T, mv1, ln_g, ln_b, out);
}

// Round 3
// 240.321 us; speedup vs baseline: 1.5887x; 1.5887x over previous
//
#include <hip/hip_runtime.h>
#include <hip/hip_bf16.h>
#include <math.h>

#define BB 16
#define SS 2048
#define DD 512
#define MM 256
#define RR 64
#define KK 16

__device__ __forceinline__ float wave_sum(float v) {
#pragma unroll
  for (int off = 32; off > 0; off >>= 1) v += __shfl_xor(v, off);
  return v;
}

__device__ __forceinline__ float sgnf(float v) {
  return (v > 0.f) ? 1.f : ((v < 0.f) ? -1.f : 0.f);
}

// exact 16th-largest |value| threshold over NREG regs/lane via ballot binary
// search on the abs-bit pattern (uint order == float order for abs values).
template <int NREG>
__device__ __forceinline__ unsigned topk_threshold(const unsigned* au) {
  unsigned lo = 0u, hi = 0x7f800000u;
  while (lo < hi) {
    unsigned mid = lo + ((hi - lo + 1u) >> 1);
    int cnt = 0;
#pragma unroll
    for (int c = 0; c < NREG; ++c)
      cnt += __popcll(__ballot(au[c] >= mid));
    if (cnt >= KK) lo = mid; else hi = mid - 1u;
  }
  return lo;
}

// ---------------------------------------------------------------------------
// LN(init_val) -> mv0 [M,D]; pt0[m,r] = (mv0[m]·rUt_w[:,r] + rUt_b[r])*r_w[r]*0.1
// ---------------------------------------------------------------------------
__global__ __launch_bounds__(256) void k_init(
    const float* __restrict__ init_val, const float* __restrict__ ln_g,
    const float* __restrict__ ln_b, const float* __restrict__ rUt_w,
    const float* __restrict__ rUt_b, const float* __restrict__ r_w,
    float* __restrict__ mv0, float* __restrict__ pt0) {
  int m = blockIdx.x, t = threadIdx.x;
  __shared__ float row[DD];
  __shared__ float red[8];
  float x0 = init_val[m * DD + t];
  float x1 = init_val[m * DD + t + 256];
  float s = wave_sum(x0 + x1);
  float sq = wave_sum(x0 * x0 + x1 * x1);
  if ((t & 63) == 0) { red[t >> 6] = s; red[4 + (t >> 6)] = sq; }
  __syncthreads();
  float mean = (red[0] + red[1] + red[2] + red[3]) * (1.0f / DD);
  float var = (red[4] + red[5] + red[6] + red[7]) * (1.0f / DD) - mean * mean;
  float rs = rsqrtf(var + 1e-5f);
  float n0 = (x0 - mean) * rs * ln_g[t] + ln_b[t];
  float n1 = (x1 - mean) * rs * ln_g[t + 256] + ln_b[t + 256];
  mv0[m * DD + t] = n0;
  mv0[m * DD + t + 256] = n1;
  row[t] = n0;
  row[t + 256] = n1;
  __syncthreads();
  if (t < RR) {
    float acc = rUt_b[t];
    for (int d = 0; d < DD; ++d) acc += row[d] * rUt_w[d * RR + t];
    pt0[m * RR + t] = acc * r_w[t] * 0.1f;
  }
}

// ---------------------------------------------------------------------------
// signed_softmax_state over 256 elements per block-row
// ---------------------------------------------------------------------------
__global__ __launch_bounds__(256) void k_state_softmax(
    const float* __restrict__ in, float* __restrict__ out) {
  int b = blockIdx.x, t = threadIdx.x;
  __shared__ float red[4];
  float v = in[b * MM + t];
  float a = fabsf(v);
  float mx = a;
#pragma unroll
  for (int off = 32; off > 0; off >>= 1) mx = fmaxf(mx, __shfl_xor(mx, off));
  if ((t & 63) == 0) red[t >> 6] = mx;
  __syncthreads();
  mx = fmaxf(fmaxf(red[0], red[1]), fmaxf(red[2], red[3]));
  __syncthreads();
  float e = expf(a - mx);
  float ssum = wave_sum(e);
  if ((t & 63) == 0) red[t >> 6] = ssum;
  __syncthreads();
  ssum = red[0] + red[1] + red[2] + red[3];
  out[b * MM + t] = sgnf(v) * e / ssum * 4.0f;
}

// ---------------------------------------------------------------------------
// C[rows,64] = A[rows,512] @ W[512,64] + bias; optional scales / transposed out
// ---------------------------------------------------------------------------
template <bool TRANS_OUT>
__global__ __launch_bounds__(256) void k_gemm512x64(
    const float* __restrict__ A, const float* __restrict__ W,
    const float* __restrict__ bias, const float* __restrict__ colscale,
    float csmul, const float* __restrict__ rowscale, float* __restrict__ C) {
  __shared__ float As[64][65];
  __shared__ float Ws[64][65];
  int tid = threadIdx.x;
  int ty = tid >> 4, tx = tid & 15;
  int row0 = blockIdx.x * 64;
  float acc[4][4] = {};
  for (int kc = 0; kc < DD; kc += 64) {
#pragma unroll
    for (int i = 0; i < 4; ++i) {
      int idx4 = i * 256 + tid;
      int r = idx4 >> 4;
      int c = (idx4 & 15) << 2;
      float4 va = *reinterpret_cast<const float4*>(
          &A[(size_t)(row0 + r) * DD + kc + c]);
      As[r][c] = va.x; As[r][c + 1] = va.y; As[r][c + 2] = va.z; As[r][c + 3] = va.w;
      float4 vw = *reinterpret_cast<const float4*>(&W[(size_t)(kc + r) * RR + c]);
      Ws[r][c] = vw.x; Ws[r][c + 1] = vw.y; Ws[r][c + 2] = vw.z; Ws[r][c + 3] = vw.w;
    }
    __syncthreads();
#pragma unroll
    for (int k = 0; k < 64; ++k) {
      float a0 = As[ty * 4 + 0][k], a1 = As[ty * 4 + 1][k];
      float a2 = As[ty * 4 + 2][k], a3 = As[ty * 4 + 3][k];
      float b0 = Ws[k][tx * 4 + 0], b1 = Ws[k][tx * 4 + 1];
      float b2 = Ws[k][tx * 4 + 2], b3 = Ws[k][tx * 4 + 3];
      acc[0][0] += a0 * b0; acc[0][1] += a0 * b1; acc[0][2] += a0 * b2; acc[0][3] += a0 * b3;
      acc[1][0] += a1 * b0; acc[1][1] += a1 * b1; acc[1][2] += a1 * b2; acc[1][3] += a1 * b3;
      acc[2][0] += a2 * b0; acc[2][1] += a2 * b1; acc[2][2] += a2 * b2; acc[2][3] += a2 * b3;
      acc[3][0] += a3 * b0; acc[3][1] += a3 * b1; acc[3][2] += a3 * b2; acc[3][3] += a3 * b3;
    }
    __syncthreads();
  }
#pragma unroll
  for (int i = 0; i < 4; ++i) {
    int rr = row0 + ty * 4 + i;
#pragma unroll
    for (int j = 0; j < 4; ++j) {
      int cc = tx * 4 + j;
      float v = acc[i][j] + bias[cc];
      if (colscale) v *= colscale[cc] * csmul;
      if (rowscale) v *= rowscale[rr];
      if (TRANS_OUT) {
        int b = rr >> 8;
        int mm = rr & 255;
        C[((size_t)b * RR + cc) * MM + mm] = v;
      } else {
        C[(size_t)rr * RR + cc] = v;
      }
    }
  }
}

// ---------------------------------------------------------------------------
// scores[b,m,j] = pt0[m,:]·ps[b,j,:]   (K=64). Tile 64m x 64j.
// ---------------------------------------------------------------------------
__global__ __launch_bounds__(256) void k_scores(
    const float* __restrict__ pt0, const float* __restrict__ ps,
    float* __restrict__ scores) {
  int b = blockIdx.z;
  int m0 = blockIdx.y * 64;
  int j0 = blockIdx.x * 64;
  __shared__ float Pt[64][65];
  __shared__ float Ps[64][65];
  int tid = threadIdx.x;
  int ty = tid >> 4, tx = tid & 15;
#pragma unroll
  for (int i = 0; i < 4; ++i) {
    int idx4 = i * 256 + tid;
    int r = idx4 >> 4;
    int c = (idx4 & 15) << 2;
    float4 vp = *reinterpret_cast<const float4*>(&pt0[(size_t)(m0 + r) * RR + c]);
    Pt[r][c] = vp.x; Pt[r][c + 1] = vp.y; Pt[r][c + 2] = vp.z; Pt[r][c + 3] = vp.w;
    float4 vs = *reinterpret_cast<const float4*>(
        &ps[((size_t)b * SS + j0 + r) * RR + c]);
    Ps[r][c] = vs.x; Ps[r][c + 1] = vs.y; Ps[r][c + 2] = vs.z; Ps[r][c + 3] = vs.w;
  }
  __syncthreads();
  float acc[4][4] = {};
#pragma unroll
  for (int k = 0; k < 64; ++k) {
    float a0 = Pt[ty * 4 + 0][k], a1 = Pt[ty * 4 + 1][k];
    float a2 = Pt[ty * 4 + 2][k], a3 = Pt[ty * 4 + 3][k];
    float b0 = Ps[tx * 4 + 0][k], b1 = Ps[tx * 4 + 1][k];
    float b2 = Ps[tx * 4 + 2][k], b3 = Ps[tx * 4 + 3][k];
    acc[0][0] += a0 * b0; acc[0][1] += a0 * b1; acc[0][2] += a0 * b2; acc[0][3] += a0 * b3;
    acc[1][0] += a1 * b0; acc[1][1] += a1 * b1; acc[1][2] += a1 * b2; acc[1][3] += a1 * b3;
    acc[2][0] += a2 * b0; acc[2][1] += a2 * b1; acc[2][2] += a2 * b2; acc[2][3] += a2 * b3;
    acc[3][0] += a3 * b0; acc[3][1] += a3 * b1; acc[3][2] += a3 * b2; acc[3][3] += a3 * b3;
  }
  float* obase = scores + (size_t)b * MM * SS;
#pragma unroll
  for (int i = 0; i < 4; ++i) {
#pragma unroll
    for (int j = 0; j < 4; ++j) {
      obase[(size_t)(m0 + ty * 4 + i) * SS + j0 + tx * 4 + j] = acc[i][j];
    }
  }
}

// ---------------------------------------------------------------------------
// One WAVE per (b,m) row. Ballot-threshold top-16 (no barriers, no shuffles
// except 1-2 rare tie picks + LN reduce) -> signed-abs-softmax -> gather ->
// LN -> mv1;  ms_w = ms0 + sum(e*state).
// ---------------------------------------------------------------------------
__global__ __launch_bounds__(256, 4) void k_write(
    const float* __restrict__ scores, const float* __restrict__ token_val,
    const float* __restrict__ token_state, const float* __restrict__ mv0,
    const float* __restrict__ ms0, const float* __restrict__ ln_g,
    const float* __restrict__ ln_b, float* __restrict__ mv1,
    float* __restrict__ ms_w) {
  int t = threadIdx.x;
  int wave = t >> 6, lane = t & 63;
  int row = blockIdx.x * 4 + wave;          // row = b*MM + m
  int b = row >> 8, m = row & 255;
  __shared__ int selj_sh[4][KK];
  const float* srow = scores + (size_t)row * SS;
  int jbase = lane * 32;
  unsigned au[32];
#pragma unroll
  for (int c4 = 0; c4 < 8; ++c4) {
    float4 q = *reinterpret_cast<const float4*>(srow + jbase + c4 * 4);
    au[c4 * 4 + 0] = __float_as_uint(q.x) & 0x7fffffffu;
    au[c4 * 4 + 1] = __float_as_uint(q.y) & 0x7fffffffu;
    au[c4 * 4 + 2] = __float_as_uint(q.z) & 0x7fffffffu;
    au[c4 * 4 + 3] = __float_as_uint(q.w) & 0x7fffffffu;
  }
  unsigned tau = topk_threshold<32>(au);
  // compact strictly-greater entries (count <= 15 by construction of tau)
  unsigned long long ltmask = (1ull << lane) - 1ull;
  int s = 0;
#pragma unroll
  for (int c = 0; c < 32; ++c) {
    bool sg = au[c] > tau;
    unsigned long long mk = __ballot(sg);
    if (sg) selj_sh[wave][s + __popcll(mk & ltmask)] = jbase + c;
    s += __popcll(mk);
  }
  // fill remaining slots with lowest-index ties (au == tau); usually 1 iter
  unsigned usedmask = 0u;
  int taken = s;
  while (taken < KK) {
    int myj = 0x7fffffff;
#pragma unroll
    for (int c = 0; c < 32; ++c)
      if (au[c] == tau && !((usedmask >> c) & 1u)) myj = min(myj, jbase + c);
    int wj = myj;
#pragma unroll
    for (int off = 32; off > 0; off >>= 1) wj = min(wj, __shfl_xor(wj, off));
    if (wj == 0x7fffffff) break;
    if (wj >= jbase && wj < jbase + 32) usedmask |= 1u << (wj - jbase);
    if (lane == 0) selj_sh[wave][taken] = wj;
    ++taken;
  }
  // softmax over the 16 selected (redundant per lane; values re-read from L1)
  int js[KK];
  float es[KK];
#pragma unroll
  for (int k = 0; k < KK; ++k) js[k] = selj_sh[wave][k];
  float mx = 0.f;
#pragma unroll
  for (int k = 0; k < KK; ++k) {
    es[k] = srow[js[k]];
    mx = fmaxf(mx, fabsf(es[k]));
  }
  float ssum = 0.f;
#pragma unroll
  for (int k = 0; k < KK; ++k) {
    float ex = expf(fabsf(es[k]) - mx);
    ssum += ex;
    es[k] = sgnf(es[k]) * ex;
  }
  float inv = 1.f / ssum;
  // gather + accumulate (8 dims per lane)
  int dbase = lane * 8;
  const float* m0row = mv0 + m * DD + dbase;
  float4 a0 = *reinterpret_cast<const float4*>(m0row);
  float4 a1 = *reinterpret_cast<const float4*>(m0row + 4);
  float acc[8] = {a0.x, a0.y, a0.z, a0.w, a1.x, a1.y, a1.z, a1.w};
  float stacc = 0.f;
#pragma unroll
  for (int k = 0; k < KK; ++k) {
    float e = es[k] * inv;
    const float* tv = token_val + ((size_t)b * SS + js[k]) * DD + dbase;
    float4 u0 = *reinterpret_cast<const float4*>(tv);
    float4 u1 = *reinterpret_cast<const float4*>(tv + 4);
    acc[0] += e * u0.x; acc[1] += e * u0.y; acc[2] += e * u0.z; acc[3] += e * u0.w;
    acc[4] += e * u1.x; acc[5] += e * u1.y; acc[6] += e * u1.z; acc[7] += e * u1.w;
    stacc += e * token_state[(size_t)b * SS + js[k]];
  }
  if (lane == 0) ms_w[row] = ms0[m] + stacc;
  // LN over the wave's 512 dims
  float s1 = 0.f, s2 = 0.f;
#pragma unroll
  for (int c = 0; c < 8; ++c) { s1 += acc[c]; s2 += acc[c] * acc[c]; }
  s1 = wave_sum(s1);
  s2 = wave_sum(s2);
  float mean = s1 * (1.0f / DD);
  float var = s2 * (1.0f / DD) - mean * mean;
  float rs = rsqrtf(var + 1e-5f);
  float4 g0 = *reinterpret_cast<const float4*>(ln_g + dbase);
  float4 g1 = *reinterpret_cast<const float4*>(ln_g + dbase + 4);
  float4 b0v = *reinterpret_cast<const float4*>(ln_b + dbase);
  float4 b1v = *reinterpret_cast<const float4*>(ln_b + dbase + 4);
  float4 o0, o1;
  o0.x = (acc[0] - mean) * rs * g0.x + b0v.x;
  o0.y = (acc[1] - mean) * rs * g0.y + b0v.y;
  o0.z = (acc[2] - mean) * rs * g0.z + b0v.z;
  o0.w = (acc[3] - mean) * rs * g0.w + b0v.w;
  o1.x = (acc[4] - mean) * rs * g1.x + b1v.x;
  o1.y = (acc[5] - mean) * rs * g1.y + b1v.y;
  o1.z = (acc[6] - mean) * rs * g1.z + b1v.z;
  o1.w = (acc[7] - mean) * rs * g1.w + b1v.w;
  float* orow = mv1 + (size_t)row * DD + dbase;
  *reinterpret_cast<float4*>(orow) = o0;
  *reinterpret_cast<float4*>(orow + 4) = o1;
}

// ---------------------------------------------------------------------------
// One WAVE per (b,m): pscores[j] = pt1[row,:]·ps1T[b,:,j] (ms1 folded in);
// ballot-threshold top-16 -> edges -> gather mv1 -> residual -> LN -> out.
// ---------------------------------------------------------------------------
__global__ __launch_bounds__(256, 4) void k_prop(
    const float* __restrict__ pt1, const float* __restrict__ ps1T,
    const float* __restrict__ mv1, const float* __restrict__ ln_g,
    const float* __restrict__ ln_b, float* __restrict__ out) {
  int t = threadIdx.x;
  int wave = t >> 6, lane = t & 63;
  int row = blockIdx.x * 4 + wave;          // row = b*MM + m
  int b = row >> 8, m = row & 255;
  __shared__ int selj_sh[4][KK];
  __shared__ float selv_sh[4][KK];
  float ptval = pt1[(size_t)row * RR + lane];
  const float* pB = ps1T + (size_t)b * RR * MM + lane * 4;
  float sc[4] = {0.f, 0.f, 0.f, 0.f};
#pragma unroll 8
  for (int r = 0; r < RR; ++r) {
    float w = __shfl(ptval, r);
    float4 pv = *reinterpret_cast<const float4*>(pB + r * MM);
    sc[0] += w * pv.x; sc[1] += w * pv.y; sc[2] += w * pv.z; sc[3] += w * pv.w;
  }
  int jbase = lane * 4;
  unsigned au[4];
#pragma unroll
  for (int c = 0; c < 4; ++c) au[c] = __float_as_uint(sc[c]) & 0x7fffffffu;
  unsigned tau = topk_threshold<4>(au);
  unsigned long long ltmask = (1ull << lane) - 1ull;
  int s = 0;
#pragma unroll
  for (int c = 0; c < 4; ++c) {
    bool sg = au[c] > tau;
    unsigned long long mk = __ballot(sg);
    if (sg) {
      int slot = s + __popcll(mk & ltmask);
      selj_sh[wave][slot] = jbase + c;
      selv_sh[wave][slot] = sc[c];
    }
    s += __popcll(mk);
  }
  unsigned usedmask = 0u;
  int taken = s;
  while (taken < KK) {
    int myj = 0x7fffffff;
#pragma unroll
    for (int c = 0; c < 4; ++c)
      if (au[c] == tau && !((usedmask >> c) & 1u)) myj = min(myj, jbase + c);
    int wj = myj;
#pragma unroll
    for (int off = 32; off > 0; off >>= 1) wj = min(wj, __shfl_xor(wj, off));
    if (wj == 0x7fffffff) break;
    if (wj >= jbase && wj < jbase + 4) {
      usedmask |= 1u << (wj - jbase);
      if (lane * 4 <= wj && wj < lane * 4 + 4) selv_sh[wave][taken] = sc[wj - jbase];
      selj_sh[wave][taken] = wj;
    }
    ++taken;
  }
  int js[KK];
  float es[KK];
#pragma unroll
  for (int k = 0; k < KK; ++k) { js[k] = selj_sh[wave][k]; es[k] = selv_sh[wave][k]; }
  float mx = 0.f;
#pragma unroll
  for (int k = 0; k < KK; ++k) mx = fmaxf(mx, fabsf(es[k]));
  float ssum = 0.f;
#pragma unroll
  for (int k = 0; k < KK; ++k) {
    float ex = expf(fabsf(es[k]) - mx);
    ssum += ex;
    es[k] = sgnf(es[k]) * ex;
  }
  float inv = 1.f / ssum;
  int dbase = lane * 8;
  const float* mrow = mv1 + (size_t)row * DD + dbase;
  float4 a0 = *reinterpret_cast<const float4*>(mrow);
  float4 a1 = *reinterpret_cast<const float4*>(mrow + 4);
  float acc[8] = {a0.x, a0.y, a0.z, a0.w, a1.x, a1.y, a1.z, a1.w};
#pragma unroll
  for (int k = 0; k < KK; ++k) {
    float e = es[k] * inv;
    const float* pv = mv1 + ((size_t)b * MM + js[k]) * DD + dbase;
    float4 u0 = *reinterpret_cast<const float4*>(pv);
    float4 u1 = *reinterpret_cast<const float4*>(pv + 4);
    acc[0] += e * u0.x; acc[1] += e * u0.y; acc[2] += e * u0.z; acc[3] += e * u0.w;
    acc[4] += e * u1.x; acc[5] += e * u1.y; acc[6] += e * u1.z; acc[7] += e * u1.w;
  }
  float s1 = 0.f, s2 = 0.f;
#pragma unroll
  for (int c = 0; c < 8; ++c) { s1 += acc[c]; s2 += acc[c] * acc[c]; }
  s1 = wave_sum(s1);
  s2 = wave_sum(s2);
  float mean = s1 * (1.0f / DD);
  float var = s2 * (1.0f / DD) - mean * mean;
  float rs = rsqrtf(var + 1e-5f);
  float4 g0 = *reinterpret_cast<const float4*>(ln_g + dbase);
  float4 g1 = *reinterpret_cast<const float4*>(ln_g + dbase + 4);
  float4 b0v = *reinterpret_cast<const float4*>(ln_b + dbase);
  float4 b1v = *reinterpret_cast<const float4*>(ln_b + dbase + 4);
  float4 o0, o1;
  o0.x = (acc[0] - mean) * rs * g0.x + b0v.x;
  o0.y = (acc[1] - mean) * rs * g0.y + b0v.y;
  o0.z = (acc[2] - mean) * rs * g0.z + b0v.z;
  o0.w = (acc[3] - mean) * rs * g0.w + b0v.w;
  o1.x = (acc[4] - mean) * rs * g1.x + b1v.x;
  o1.y = (acc[5] - mean) * rs * g1.y + b1v.y;
  o1.z = (acc[6] - mean) * rs * g1.z + b1v.z;
  o1.w = (acc[7] - mean) * rs * g1.w + b1v.w;
  float* orow = out + (size_t)row * DD + dbase;
  *reinterpret_cast<float4*>(orow) = o0;
  *reinterpret_cast<float4*>(orow + 4) = o1;
}

extern "C" void kernel_launch(void* const* d_in, const int* in_sizes, int n_in,
                              void* d_out, int out_size, void* d_ws,
                              size_t ws_size, hipStream_t stream) {
  const float* token_val = (const float*)d_in[0];
  const float* token_state = (const float*)d_in[1];
  const float* init_state = (const float*)d_in[2];
  const float* init_val = (const float*)d_in[3];
  const float* rUs_w = (const float*)d_in[4];
  const float* rUs_b = (const float*)d_in[5];
  const float* rUt_w = (const float*)d_in[6];
  const float* rUt_b = (const float*)d_in[7];
  const float* r_w = (const float*)d_in[8];
  const float* pUs_w = (const float*)d_in[9];
  const float* pUs_b = (const float*)d_in[10];
  const float* pUt_w = (const float*)d_in[11];
  const float* pUt_b = (const float*)d_in[12];
  const float* p_w = (const float*)d_in[13];
  const float* ln_g = (const float*)d_in[14];
  const float* ln_b = (const float*)d_in[15];
  float* out = (float*)d_out;

  float* ws = (float*)d_ws;
  float* mv0 = ws;    ws += MM * DD;
  float* pt0 = ws;    ws += MM * RR;
  float* ms0 = ws;    ws += MM;
  float* ps = ws;     ws += (size_t)BB * SS * RR;
  float* scores = ws; ws += (size_t)BB * MM * SS;
  float* mv1 = ws;    ws += (size_t)BB * MM * DD;
  float* ms_w = ws;   ws += BB * MM;
  float* ms1 = ws;    ws += BB * MM;
  float* pt1 = ws;    ws += (size_t)BB * MM * RR;
  float* ps1T = ws;   ws += (size_t)BB * RR * MM;

  k_init<<<MM, 256, 0, stream>>>(init_val, ln_g, ln_b, rUt_w, rUt_b, r_w, mv0, pt0);
  k_state_softmax<<<1, 256, 0, stream>>>(init_state, ms0);
  k_gemm512x64<false><<<(BB * SS) / 64, 256, 0, stream>>>(
      token_val, rUs_w, rUs_b, nullptr, 1.f, nullptr, ps);
  dim3 gs(SS / 64, MM / 64, BB);
  k_scores<<<gs, 256, 0, stream>>>(pt0, ps, scores);
  k_write<<<(BB * MM) / 4, 256, 0, stream>>>(scores, token_val, token_state,
                                             mv0, ms0, ln_g, ln_b, mv1, ms_w);
  k_state_softmax<<<BB, 256, 0, stream>>>(ms_w, ms1);
  k_gemm512x64<false><<<(BB * MM) / 64, 256, 0, stream>>>(
      mv1, pUt_w, pUt_b, p_w, 0.1f, nullptr, pt1);
  k_gemm512x64<true><<<(BB * MM) / 64, 256, 0, stream>>>(
      mv1, pUs_w, pUs_b, nullptr, 1.f, ms1, ps1T);
  k_prop<<<(BB * MM) / 4, 256, 0, stream>>>(pt1, ps1T, mv1, ln_g, ln_b, out);
}

// Round 4
// 207.964 us; speedup vs baseline: 1.8358x; 1.1556x over previous
//
#include <hip/hip_runtime.h>
#include <hip/hip_bf16.h>
#include <math.h>

#define BB 16
#define SS 2048
#define DD 512
#define MM 256
#define RR 64
#define KK 16

__device__ __forceinline__ float wave_sum(float v) {
#pragma unroll
  for (int off = 32; off > 0; off >>= 1) v += __shfl_xor(v, off);
  return v;
}

__device__ __forceinline__ float sgnf(float v) {
  return (v > 0.f) ? 1.f : ((v < 0.f) ? -1.f : 0.f);
}

// ---------------------------------------------------------------------------
// LN(init_val) -> mv0 [M,D]; pt0[m,r] = (mv0[m]·rUt_w[:,r] + rUt_b[r])*r_w[r]*0.1
// ---------------------------------------------------------------------------
__global__ __launch_bounds__(256) void k_init(
    const float* __restrict__ init_val, const float* __restrict__ ln_g,
    const float* __restrict__ ln_b, const float* __restrict__ rUt_w,
    const float* __restrict__ rUt_b, const float* __restrict__ r_w,
    float* __restrict__ mv0, float* __restrict__ pt0) {
  int m = blockIdx.x, t = threadIdx.x;
  __shared__ float row[DD];
  __shared__ float red[8];
  float x0 = init_val[m * DD + t];
  float x1 = init_val[m * DD + t + 256];
  float s = wave_sum(x0 + x1);
  float sq = wave_sum(x0 * x0 + x1 * x1);
  if ((t & 63) == 0) { red[t >> 6] = s; red[4 + (t >> 6)] = sq; }
  __syncthreads();
  float mean = (red[0] + red[1] + red[2] + red[3]) * (1.0f / DD);
  float var = (red[4] + red[5] + red[6] + red[7]) * (1.0f / DD) - mean * mean;
  float rs = rsqrtf(var + 1e-5f);
  float n0 = (x0 - mean) * rs * ln_g[t] + ln_b[t];
  float n1 = (x1 - mean) * rs * ln_g[t + 256] + ln_b[t + 256];
  mv0[m * DD + t] = n0;
  mv0[m * DD + t + 256] = n1;
  row[t] = n0;
  row[t + 256] = n1;
  __syncthreads();
  if (t < RR) {
    float acc = rUt_b[t];
    for (int d = 0; d < DD; ++d) acc += row[d] * rUt_w[d * RR + t];
    pt0[m * RR + t] = acc * r_w[t] * 0.1f;
  }
}

// ---------------------------------------------------------------------------
// signed_softmax_state over 256 elements per block-row
// ---------------------------------------------------------------------------
__global__ __launch_bounds__(256) void k_state_softmax(
    const float* __restrict__ in, float* __restrict__ out) {
  int b = blockIdx.x, t = threadIdx.x;
  __shared__ float red[4];
  float v = in[b * MM + t];
  float a = fabsf(v);
  float mx = a;
#pragma unroll
  for (int off = 32; off > 0; off >>= 1) mx = fmaxf(mx, __shfl_xor(mx, off));
  if ((t & 63) == 0) red[t >> 6] = mx;
  __syncthreads();
  mx = fmaxf(fmaxf(red[0], red[1]), fmaxf(red[2], red[3]));
  __syncthreads();
  float e = expf(a - mx);
  float ssum = wave_sum(e);
  if ((t & 63) == 0) red[t >> 6] = ssum;
  __syncthreads();
  ssum = red[0] + red[1] + red[2] + red[3];
  out[b * MM + t] = sgnf(v) * e / ssum * 4.0f;
}

// ---------------------------------------------------------------------------
// C[rows,64] = A[rows,512] @ W[512,64] + bias; optional scales / transposed out
// ---------------------------------------------------------------------------
template <bool TRANS_OUT>
__global__ __launch_bounds__(256) void k_gemm512x64(
    const float* __restrict__ A, const float* __restrict__ W,
    const float* __restrict__ bias, const float* __restrict__ colscale,
    float csmul, const float* __restrict__ rowscale, float* __restrict__ C) {
  __shared__ float As[64][65];
  __shared__ float Ws[64][65];
  int tid = threadIdx.x;
  int ty = tid >> 4, tx = tid & 15;
  int row0 = blockIdx.x * 64;
  float acc[4][4] = {};
  for (int kc = 0; kc < DD; kc += 64) {
#pragma unroll
    for (int i = 0; i < 4; ++i) {
      int idx4 = i * 256 + tid;
      int r = idx4 >> 4;
      int c = (idx4 & 15) << 2;
      float4 va = *reinterpret_cast<const float4*>(
          &A[(size_t)(row0 + r) * DD + kc + c]);
      As[r][c] = va.x; As[r][c + 1] = va.y; As[r][c + 2] = va.z; As[r][c + 3] = va.w;
      float4 vw = *reinterpret_cast<const float4*>(&W[(size_t)(kc + r) * RR + c]);
      Ws[r][c] = vw.x; Ws[r][c + 1] = vw.y; Ws[r][c + 2] = vw.z; Ws[r][c + 3] = vw.w;
    }
    __syncthreads();
#pragma unroll
    for (int k = 0; k < 64; ++k) {
      float a0 = As[ty * 4 + 0][k], a1 = As[ty * 4 + 1][k];
      float a2 = As[ty * 4 + 2][k], a3 = As[ty * 4 + 3][k];
      float b0 = Ws[k][tx * 4 + 0], b1 = Ws[k][tx * 4 + 1];
      float b2 = Ws[k][tx * 4 + 2], b3 = Ws[k][tx * 4 + 3];
      acc[0][0] += a0 * b0; acc[0][1] += a0 * b1; acc[0][2] += a0 * b2; acc[0][3] += a0 * b3;
      acc[1][0] += a1 * b0; acc[1][1] += a1 * b1; acc[1][2] += a1 * b2; acc[1][3] += a1 * b3;
      acc[2][0] += a2 * b0; acc[2][1] += a2 * b1; acc[2][2] += a2 * b2; acc[2][3] += a2 * b3;
      acc[3][0] += a3 * b0; acc[3][1] += a3 * b1; acc[3][2] += a3 * b2; acc[3][3] += a3 * b3;
    }
    __syncthreads();
  }
#pragma unroll
  for (int i = 0; i < 4; ++i) {
    int rr = row0 + ty * 4 + i;
#pragma unroll
    for (int j = 0; j < 4; ++j) {
      int cc = tx * 4 + j;
      float v = acc[i][j] + bias[cc];
      if (colscale) v *= colscale[cc] * csmul;
      if (rowscale) v *= rowscale[rr];
      if (TRANS_OUT) {
        int b = rr >> 8;
        int mm = rr & 255;
        C[((size_t)b * RR + cc) * MM + mm] = v;
      } else {
        C[(size_t)rr * RR + cc] = v;
      }
    }
  }
}

// ---------------------------------------------------------------------------
// scores[b,m,j] = pt0[m,:]·ps[b,j,:]   (K=64). Tile 64m x 64j.
// ---------------------------------------------------------------------------
__global__ __launch_bounds__(256) void k_scores(
    const float* __restrict__ pt0, const float* __restrict__ ps,
    float* __restrict__ scores) {
  int b = blockIdx.z;
  int m0 = blockIdx.y * 64;
  int j0 = blockIdx.x * 64;
  __shared__ float Pt[64][65];
  __shared__ float Ps[64][65];
  int tid = threadIdx.x;
  int ty = tid >> 4, tx = tid & 15;
#pragma unroll
  for (int i = 0; i < 4; ++i) {
    int idx4 = i * 256 + tid;
    int r = idx4 >> 4;
    int c = (idx4 & 15) << 2;
    float4 vp = *reinterpret_cast<const float4*>(&pt0[(size_t)(m0 + r) * RR + c]);
    Pt[r][c] = vp.x; Pt[r][c + 1] = vp.y; Pt[r][c + 2] = vp.z; Pt[r][c + 3] = vp.w;
    float4 vs = *reinterpret_cast<const float4*>(
        &ps[((size_t)b * SS + j0 + r) * RR + c]);
    Ps[r][c] = vs.x; Ps[r][c + 1] = vs.y; Ps[r][c + 2] = vs.z; Ps[r][c + 3] = vs.w;
  }
  __syncthreads();
  float acc[4][4] = {};
#pragma unroll
  for (int k = 0; k < 64; ++k) {
    float a0 = Pt[ty * 4 + 0][k], a1 = Pt[ty * 4 + 1][k];
    float a2 = Pt[ty * 4 + 2][k], a3 = Pt[ty * 4 + 3][k];
    float b0 = Ps[tx * 4 + 0][k], b1 = Ps[tx * 4 + 1][k];
    float b2 = Ps[tx * 4 + 2][k], b3 = Ps[tx * 4 + 3][k];
    acc[0][0] += a0 * b0; acc[0][1] += a0 * b1; acc[0][2] += a0 * b2; acc[0][3] += a0 * b3;
    acc[1][0] += a1 * b0; acc[1][1] += a1 * b1; acc[1][2] += a1 * b2; acc[1][3] += a1 * b3;
    acc[2][0] += a2 * b0; acc[2][1] += a2 * b1; acc[2][2] += a2 * b2; acc[2][3] += a2 * b3;
    acc[3][0] += a3 * b0; acc[3][1] += a3 * b1; acc[3][2] += a3 * b2; acc[3][3] += a3 * b3;
  }
  float* obase = scores + (size_t)b * MM * SS;
#pragma unroll
  for (int i = 0; i < 4; ++i) {
#pragma unroll
    for (int j = 0; j < 4; ++j) {
      obase[(size_t)(m0 + ty * 4 + i) * SS + j0 + tx * 4 + j] = acc[i][j];
    }
  }
}

// ---------------------------------------------------------------------------
// One WAVE per (b,m) row. Score row staged in LDS (no register array -> no
// spill). Ballot binary-search threshold with cnt==16 early exit; compact;
// signed-abs-softmax; gather token rows; LN -> mv1. XCD b-affinity swizzle.
// ---------------------------------------------------------------------------
__global__ __launch_bounds__(256) void k_write(
    const float* __restrict__ scores, const float* __restrict__ token_val,
    const float* __restrict__ token_state, const float* __restrict__ mv0,
    const float* __restrict__ ms0, const float* __restrict__ ln_g,
    const float* __restrict__ ln_b, float* __restrict__ mv1,
    float* __restrict__ ms_w) {
  int t = threadIdx.x;
  int wave = t >> 6, lane = t & 63;
  // XCD-affinity swizzle: xcd = blockIdx%8 (heuristic RR dispatch); give each
  // xcd two full batches so the token_val gather working set ~ 2x4MB per L2.
  int i = blockIdx.x;                 // 0..1023
  int slot = i >> 3;                  // 0..127
  int b = 2 * (i & 7) + (slot >> 6);  // two b per xcd
  int m = (slot & 63) * 4 + wave;
  int row = b * MM + m;
  __shared__ float srl[4][SS];        // 8KB per wave
  __shared__ int selj_sh[4][KK];
  float4* srl4 = reinterpret_cast<float4*>(&srl[wave][0]);
  const float* srow = scores + (size_t)row * SS;
  // stage row -> LDS, track max |bits|
  unsigned maxa = 0u;
#pragma unroll
  for (int ch = 0; ch < 8; ++ch) {
    float4 q = *reinterpret_cast<const float4*>(srow + (ch * 64 + lane) * 4);
    srl4[ch * 64 + lane] = q;
    maxa = max(maxa, __float_as_uint(q.x) & 0x7fffffffu);
    maxa = max(maxa, __float_as_uint(q.y) & 0x7fffffffu);
    maxa = max(maxa, __float_as_uint(q.z) & 0x7fffffffu);
    maxa = max(maxa, __float_as_uint(q.w) & 0x7fffffffu);
  }
#pragma unroll
  for (int off = 32; off > 0; off >>= 1)
    maxa = max(maxa, (unsigned)__shfl_xor((int)maxa, off));
  // binary search for the top-16 threshold; early-exit when set is exact
  unsigned lo = 0u, hi = maxa, thr = 0u;
  bool early = false;
  while (lo < hi) {
    unsigned mid = lo + ((hi - lo + 1u) >> 1);
    int cnt = 0;
#pragma unroll
    for (int ch = 0; ch < 8; ++ch) {
      float4 q = srl4[ch * 64 + lane];
      cnt += __popcll(__ballot((__float_as_uint(q.x) & 0x7fffffffu) >= mid));
      cnt += __popcll(__ballot((__float_as_uint(q.y) & 0x7fffffffu) >= mid));
      cnt += __popcll(__ballot((__float_as_uint(q.z) & 0x7fffffffu) >= mid));
      cnt += __popcll(__ballot((__float_as_uint(q.w) & 0x7fffffffu) >= mid));
    }
    if (cnt == KK) { thr = mid; early = true; break; }
    if (cnt > KK) lo = mid; else hi = mid - 1u;
  }
  if (!early) thr = lo;
  // compact selected indices (ordered); collect tie mask for the rare path
  unsigned long long ltmask = (1ull << lane) - 1ull;
  int s = 0;
  unsigned tiemask = 0u;
#pragma unroll
  for (int ch = 0; ch < 8; ++ch) {
    float4 q = srl4[ch * 64 + lane];
    unsigned a4[4] = {__float_as_uint(q.x) & 0x7fffffffu,
                      __float_as_uint(q.y) & 0x7fffffffu,
                      __float_as_uint(q.z) & 0x7fffffffu,
                      __float_as_uint(q.w) & 0x7fffffffu};
#pragma unroll
    for (int cc = 0; cc < 4; ++cc) {
      bool sg = early ? (a4[cc] >= thr) : (a4[cc] > thr);
      unsigned long long mk = __ballot(sg);
      if (sg) selj_sh[wave][s + __popcll(mk & ltmask)] = ch * 256 + lane * 4 + cc;
      s += __popcll(mk);
      if (!early && a4[cc] == thr) tiemask |= 1u << (ch * 4 + cc);
    }
  }
  int taken = s;
  while (taken < KK) {   // rare: fill ties by ascending index
    int myj = 0x7fffffff;
#pragma unroll
    for (int c = 0; c < 32; ++c)
      if ((tiemask >> c) & 1u) {
        int j = (c >> 2) * 256 + lane * 4 + (c & 3);
        myj = min(myj, j);
      }
    int wj = myj;
#pragma unroll
    for (int off = 32; off > 0; off >>= 1) wj = min(wj, __shfl_xor(wj, off));
    if (wj == 0x7fffffff) break;
    if (((wj >> 2) & 63) == lane) tiemask &= ~(1u << (((wj >> 8) << 2) | (wj & 3)));
    if (lane == 0) selj_sh[wave][taken] = wj;
    ++taken;
  }
  // signed-abs-softmax over selected (values from LDS, broadcast reads)
  int js[KK];
  float es[KK];
#pragma unroll
  for (int k = 0; k < KK; ++k) {
    js[k] = selj_sh[wave][k];
    es[k] = srl[wave][js[k]];
  }
  float mx = 0.f;
#pragma unroll
  for (int k = 0; k < KK; ++k) mx = fmaxf(mx, fabsf(es[k]));
  float ssum = 0.f;
#pragma unroll
  for (int k = 0; k < KK; ++k) {
    float ex = expf(fabsf(es[k]) - mx);
    ssum += ex;
    es[k] = sgnf(es[k]) * ex;
  }
  float inv = 1.f / ssum;
  // gather + accumulate (8 dims per lane)
  int dbase = lane * 8;
  const float* m0row = mv0 + m * DD + dbase;
  float4 a0 = *reinterpret_cast<const float4*>(m0row);
  float4 a1 = *reinterpret_cast<const float4*>(m0row + 4);
  float acc[8] = {a0.x, a0.y, a0.z, a0.w, a1.x, a1.y, a1.z, a1.w};
  float stacc = 0.f;
#pragma unroll
  for (int k = 0; k < KK; ++k) {
    float e = es[k] * inv;
    const float* tv = token_val + ((size_t)b * SS + js[k]) * DD + dbase;
    float4 u0 = *reinterpret_cast<const float4*>(tv);
    float4 u1 = *reinterpret_cast<const float4*>(tv + 4);
    acc[0] += e * u0.x; acc[1] += e * u0.y; acc[2] += e * u0.z; acc[3] += e * u0.w;
    acc[4] += e * u1.x; acc[5] += e * u1.y; acc[6] += e * u1.z; acc[7] += e * u1.w;
    stacc += e * token_state[(size_t)b * SS + js[k]];
  }
  if (lane == 0) ms_w[row] = ms0[m] + stacc;
  // LN over the wave's 512 dims
  float s1 = 0.f, s2 = 0.f;
#pragma unroll
  for (int c = 0; c < 8; ++c) { s1 += acc[c]; s2 += acc[c] * acc[c]; }
  s1 = wave_sum(s1);
  s2 = wave_sum(s2);
  float mean = s1 * (1.0f / DD);
  float var = s2 * (1.0f / DD) - mean * mean;
  float rs = rsqrtf(var + 1e-5f);
  float4 g0 = *reinterpret_cast<const float4*>(ln_g + dbase);
  float4 g1 = *reinterpret_cast<const float4*>(ln_g + dbase + 4);
  float4 b0v = *reinterpret_cast<const float4*>(ln_b + dbase);
  float4 b1v = *reinterpret_cast<const float4*>(ln_b + dbase + 4);
  float4 o0, o1;
  o0.x = (acc[0] - mean) * rs * g0.x + b0v.x;
  o0.y = (acc[1] - mean) * rs * g0.y + b0v.y;
  o0.z = (acc[2] - mean) * rs * g0.z + b0v.z;
  o0.w = (acc[3] - mean) * rs * g0.w + b0v.w;
  o1.x = (acc[4] - mean) * rs * g1.x + b1v.x;
  o1.y = (acc[5] - mean) * rs * g1.y + b1v.y;
  o1.z = (acc[6] - mean) * rs * g1.z + b1v.z;
  o1.w = (acc[7] - mean) * rs * g1.w + b1v.w;
  float* orow = mv1 + (size_t)row * DD + dbase;
  *reinterpret_cast<float4*>(orow) = o0;
  *reinterpret_cast<float4*>(orow + 4) = o1;
}

// ---------------------------------------------------------------------------
// One WAVE per (b,m): pscores[j] = pt1[row,:]·ps1T[b,:,j] (ms1 folded in);
// ballot-threshold top-16 -> edges -> gather mv1 -> residual -> LN -> out.
// ---------------------------------------------------------------------------
__global__ __launch_bounds__(256, 4) void k_prop(
    const float* __restrict__ pt1, const float* __restrict__ ps1T,
    const float* __restrict__ mv1, const float* __restrict__ ln_g,
    const float* __restrict__ ln_b, float* __restrict__ out) {
  int t = threadIdx.x;
  int wave = t >> 6, lane = t & 63;
  int row = blockIdx.x * 4 + wave;          // row = b*MM + m
  int b = row >> 8, m = row & 255;
  __shared__ int selj_sh[4][KK];
  __shared__ float selv_sh[4][KK];
  float ptval = pt1[(size_t)row * RR + lane];
  const float* pB = ps1T + (size_t)b * RR * MM + lane * 4;
  float sc[4] = {0.f, 0.f, 0.f, 0.f};
#pragma unroll 8
  for (int r = 0; r < RR; ++r) {
    float w = __shfl(ptval, r);
    float4 pv = *reinterpret_cast<const float4*>(pB + r * MM);
    sc[0] += w * pv.x; sc[1] += w * pv.y; sc[2] += w * pv.z; sc[3] += w * pv.w;
  }
  int jbase = lane * 4;
  unsigned au[4];
#pragma unroll
  for (int c = 0; c < 4; ++c) au[c] = __float_as_uint(sc[c]) & 0x7fffffffu;
  unsigned lo = 0u, hi = 0x7f800000u, thr = 0u;
  bool early = false;
  while (lo < hi) {
    unsigned mid = lo + ((hi - lo + 1u) >> 1);
    int cnt = 0;
#pragma unroll
    for (int c = 0; c < 4; ++c) cnt += __popcll(__ballot(au[c] >= mid));
    if (cnt == KK) { thr = mid; early = true; break; }
    if (cnt > KK) lo = mid; else hi = mid - 1u;
  }
  if (!early) thr = lo;
  unsigned long long ltmask = (1ull << lane) - 1ull;
  int s = 0;
  unsigned tiemask = 0u;
#pragma unroll
  for (int c = 0; c < 4; ++c) {
    bool sg = early ? (au[c] >= thr) : (au[c] > thr);
    unsigned long long mk = __ballot(sg);
    if (sg) {
      int slot = s + __popcll(mk & ltmask);
      selj_sh[wave][slot] = jbase + c;
      selv_sh[wave][slot] = sc[c];
    }
    s += __popcll(mk);
    if (!early && au[c] == thr) tiemask |= 1u << c;
  }
  int taken = s;
  while (taken < KK) {
    int myj = 0x7fffffff;
#pragma unroll
    for (int c = 0; c < 4; ++c)
      if ((tiemask >> c) & 1u) myj = min(myj, jbase + c);
    int wj = myj;
#pragma unroll
    for (int off = 32; off > 0; off >>= 1) wj = min(wj, __shfl_xor(wj, off));
    if (wj == 0x7fffffff) break;
    if (wj >= jbase && wj < jbase + 4) {
      tiemask &= ~(1u << (wj - jbase));
      selv_sh[wave][taken] = sc[wj - jbase];
      if (lane == (wj >> 2)) selj_sh[wave][taken] = wj;
    }
    ++taken;
  }
  int js[KK];
  float es[KK];
#pragma unroll
  for (int k = 0; k < KK; ++k) { js[k] = selj_sh[wave][k]; es[k] = selv_sh[wave][k]; }
  float mx = 0.f;
#pragma unroll
  for (int k = 0; k < KK; ++k) mx = fmaxf(mx, fabsf(es[k]));
  float ssum = 0.f;
#pragma unroll
  for (int k = 0; k < KK; ++k) {
    float ex = expf(fabsf(es[k]) - mx);
    ssum += ex;
    es[k] = sgnf(es[k]) * ex;
  }
  float inv = 1.f / ssum;
  int dbase = lane * 8;
  const float* mrow = mv1 + (size_t)row * DD + dbase;
  float4 a0 = *reinterpret_cast<const float4*>(mrow);
  float4 a1 = *reinterpret_cast<const float4*>(mrow + 4);
  float acc[8] = {a0.x, a0.y, a0.z, a0.w, a1.x, a1.y, a1.z, a1.w};
#pragma unroll
  for (int k = 0; k < KK; ++k) {
    float e = es[k] * inv;
    const float* pv = mv1 + ((size_t)b * MM + js[k]) * DD + dbase;
    float4 u0 = *reinterpret_cast<const float4*>(pv);
    float4 u1 = *reinterpret_cast<const float4*>(pv + 4);
    acc[0] += e * u0.x; acc[1] += e * u0.y; acc[2] += e * u0.z; acc[3] += e * u0.w;
    acc[4] += e * u1.x; acc[5] += e * u1.y; acc[6] += e * u1.z; acc[7] += e * u1.w;
  }
  float s1 = 0.f, s2 = 0.f;
#pragma unroll
  for (int c = 0; c < 8; ++c) { s1 += acc[c]; s2 += acc[c] * acc[c]; }
  s1 = wave_sum(s1);
  s2 = wave_sum(s2);
  float mean = s1 * (1.0f / DD);
  float var = s2 * (1.0f / DD) - mean * mean;
  float rs = rsqrtf(var + 1e-5f);
  float4 g0 = *reinterpret_cast<const float4*>(ln_g + dbase);
  float4 g1 = *reinterpret_cast<const float4*>(ln_g + dbase + 4);
  float4 b0v = *reinterpret_cast<const float4*>(ln_b + dbase);
  float4 b1v = *reinterpret_cast<const float4*>(ln_b + dbase + 4);
  float4 o0, o1;
  o0.x = (acc[0] - mean) * rs * g0.x + b0v.x;
  o0.y = (acc[1] - mean) * rs * g0.y + b0v.y;
  o0.z = (acc[2] - mean) * rs * g0.z + b0v.z;
  o0.w = (acc[3] - mean) * rs * g0.w + b0v.w;
  o1.x = (acc[4] - mean) * rs * g1.x + b1v.x;
  o1.y = (acc[5] - mean) * rs * g1.y + b1v.y;
  o1.z = (acc[6] - mean) * rs * g1.z + b1v.z;
  o1.w = (acc[7] - mean) * rs * g1.w + b1v.w;
  float* orow = out + (size_t)row * DD + dbase;
  *reinterpret_cast<float4*>(orow) = o0;
  *reinterpret_cast<float4*>(orow + 4) = o1;
}

extern "C" void kernel_launch(void* const* d_in, const int* in_sizes, int n_in,
                              void* d_out, int out_size, void* d_ws,
                              size_t ws_size, hipStream_t stream) {
  const float* token_val = (const float*)d_in[0];
  const float* token_state = (const float*)d_in[1];
  const float* init_state = (const float*)d_in[2];
  const float* init_val = (const float*)d_in[3];
  const float* rUs_w = (const float*)d_in[4];
  const float* rUs_b = (const float*)d_in[5];
  const float* rUt_w = (const float*)d_in[6];
  const float* rUt_b = (const float*)d_in[7];
  const float* r_w = (const float*)d_in[8];
  const float* pUs_w = (const float*)d_in[9];
  const float* pUs_b = (const float*)d_in[10];
  const float* pUt_w = (const float*)d_in[11];
  const float* pUt_b = (const float*)d_in[12];
  const float* p_w = (const float*)d_in[13];
  const float* ln_g = (const float*)d_in[14];
  const float* ln_b = (const float*)d_in[15];
  float* out = (float*)d_out;

  float* ws = (float*)d_ws;
  float* mv0 = ws;    ws += MM * DD;
  float* pt0 = ws;    ws += MM * RR;
  float* ms0 = ws;    ws += MM;
  float* ps = ws;     ws += (size_t)BB * SS * RR;
  float* scores = ws; ws += (size_t)BB * MM * SS;
  float* mv1 = ws;    ws += (size_t)BB * MM * DD;
  float* ms_w = ws;   ws += BB * MM;
  float* ms1 = ws;    ws += BB * MM;
  float* pt1 = ws;    ws += (size_t)BB * MM * RR;
  float* ps1T = ws;   ws += (size_t)BB * RR * MM;

  k_init<<<MM, 256, 0, stream>>>(init_val, ln_g, ln_b, rUt_w, rUt_b, r_w, mv0, pt0);
  k_state_softmax<<<1, 256, 0, stream>>>(init_state, ms0);
  k_gemm512x64<false><<<(BB * SS) / 64, 256, 0, stream>>>(
      token_val, rUs_w, rUs_b, nullptr, 1.f, nullptr, ps);
  dim3 gs(SS / 64, MM / 64, BB);
  k_scores<<<gs, 256, 0, stream>>>(pt0, ps, scores);
  k_write<<<(BB * MM) / 4, 256, 0, stream>>>(scores, token_val, token_state,
                                             mv0, ms0, ln_g, ln_b, mv1, ms_w);
  k_state_softmax<<<BB, 256, 0, stream>>>(ms_w, ms1);
  k_gemm512x64<false><<<(BB * MM) / 64, 256, 0, stream>>>(
      mv1, pUt_w, pUt_b, p_w, 0.1f, nullptr, pt1);
  k_gemm512x64<true><<<(BB * MM) / 64, 256, 0, stream>>>(
      mv1, pUs_w, pUs_b, nullptr, 1.f, ms1, ps1T);
  k_prop<<<(BB * MM) / 4, 256, 0, stream>>>(pt1, ps1T, mv1, ln_g, ln_b, out);
}

// Round 5
// 197.721 us; speedup vs baseline: 1.9309x; 1.0518x over previous
//
#include <hip/hip_runtime.h>
#include <hip/hip_bf16.h>
#include <math.h>

#define BB 16
#define SS 2048
#define DD 512
#define MM 256
#define RR 64
#define KK 16

__device__ __forceinline__ float wave_sum(float v) {
#pragma unroll
  for (int off = 32; off > 0; off >>= 1) v += __shfl_xor(v, off);
  return v;
}

__device__ __forceinline__ float sgnf(float v) {
  return (v > 0.f) ? 1.f : ((v < 0.f) ? -1.f : 0.f);
}

// ---------------------------------------------------------------------------
// LN(init_val) -> mv0 [M,D]; pt0[m,r] = (mv0[m]·rUt_w[:,r] + rUt_b[r])*r_w[r]*0.1
// ---------------------------------------------------------------------------
__global__ __launch_bounds__(256) void k_init(
    const float* __restrict__ init_val, const float* __restrict__ ln_g,
    const float* __restrict__ ln_b, const float* __restrict__ rUt_w,
    const float* __restrict__ rUt_b, const float* __restrict__ r_w,
    float* __restrict__ mv0, float* __restrict__ pt0) {
  int m = blockIdx.x, t = threadIdx.x;
  __shared__ float row[DD];
  __shared__ float red[8];
  float x0 = init_val[m * DD + t];
  float x1 = init_val[m * DD + t + 256];
  float s = wave_sum(x0 + x1);
  float sq = wave_sum(x0 * x0 + x1 * x1);
  if ((t & 63) == 0) { red[t >> 6] = s; red[4 + (t >> 6)] = sq; }
  __syncthreads();
  float mean = (red[0] + red[1] + red[2] + red[3]) * (1.0f / DD);
  float var = (red[4] + red[5] + red[6] + red[7]) * (1.0f / DD) - mean * mean;
  float rs = rsqrtf(var + 1e-5f);
  float n0 = (x0 - mean) * rs * ln_g[t] + ln_b[t];
  float n1 = (x1 - mean) * rs * ln_g[t + 256] + ln_b[t + 256];
  mv0[m * DD + t] = n0;
  mv0[m * DD + t + 256] = n1;
  row[t] = n0;
  row[t + 256] = n1;
  __syncthreads();
  if (t < RR) {
    float acc = rUt_b[t];
    for (int d = 0; d < DD; ++d) acc += row[d] * rUt_w[d * RR + t];
    pt0[m * RR + t] = acc * r_w[t] * 0.1f;
  }
}

// ---------------------------------------------------------------------------
// signed_softmax_state over 256 elements per block-row
// ---------------------------------------------------------------------------
__global__ __launch_bounds__(256) void k_state_softmax(
    const float* __restrict__ in, float* __restrict__ out) {
  int b = blockIdx.x, t = threadIdx.x;
  __shared__ float red[4];
  float v = in[b * MM + t];
  float a = fabsf(v);
  float mx = a;
#pragma unroll
  for (int off = 32; off > 0; off >>= 1) mx = fmaxf(mx, __shfl_xor(mx, off));
  if ((t & 63) == 0) red[t >> 6] = mx;
  __syncthreads();
  mx = fmaxf(fmaxf(red[0], red[1]), fmaxf(red[2], red[3]));
  __syncthreads();
  float e = expf(a - mx);
  float ssum = wave_sum(e);
  if ((t & 63) == 0) red[t >> 6] = ssum;
  __syncthreads();
  ssum = red[0] + red[1] + red[2] + red[3];
  out[b * MM + t] = sgnf(v) * e / ssum * 4.0f;
}

// ---------------------------------------------------------------------------
// Skinny GEMM body: C[rows,64] = A[rows,512] @ W[512,64] + bias.
// 32-row tile / block, 256 threads, micro 2x4. A staged in LDS (broadcast
// reads, pad 132 -> conflict-free); W read directly from global (L1/L2-hot,
// VMEM pipe) - keeps W traffic off the LDS pipe entirely.
// ---------------------------------------------------------------------------
template <bool TRANS_OUT>
__device__ __forceinline__ void gemm_skinny_body(
    const float* __restrict__ A, const float* __restrict__ W,
    const float* __restrict__ bias, const float* __restrict__ colscale,
    float csmul, const float* __restrict__ rowscale, float* __restrict__ C,
    int row0, float (*As)[132]) {
  int tid = threadIdx.x;
  int ty = tid >> 4, tx = tid & 15;
  float acc[2][4] = {};
  for (int kc = 0; kc < DD; kc += 128) {
#pragma unroll
    for (int i = 0; i < 4; ++i) {
      int s4 = i * 256 + tid;   // 1024 float4 slots (32 rows x 32 f4)
      int r = s4 >> 5;
      int c4 = s4 & 31;
      float4 v = *reinterpret_cast<const float4*>(
          &A[(size_t)(row0 + r) * DD + kc + c4 * 4]);
      *reinterpret_cast<float4*>(&As[r][c4 * 4]) = v;
    }
    __syncthreads();
    const float* Wp = W + (size_t)kc * RR + tx * 4;
#pragma unroll 8
    for (int k = 0; k < 128; ++k) {
      float4 w4 = *reinterpret_cast<const float4*>(Wp + (size_t)k * RR);
      float a0 = As[ty][k];
      float a1 = As[ty + 16][k];
      acc[0][0] += a0 * w4.x; acc[0][1] += a0 * w4.y;
      acc[0][2] += a0 * w4.z; acc[0][3] += a0 * w4.w;
      acc[1][0] += a1 * w4.x; acc[1][1] += a1 * w4.y;
      acc[1][2] += a1 * w4.z; acc[1][3] += a1 * w4.w;
    }
    __syncthreads();
  }
#pragma unroll
  for (int i = 0; i < 2; ++i) {
    int rr = row0 + ty + i * 16;
#pragma unroll
    for (int j = 0; j < 4; ++j) {
      int cc = tx * 4 + j;
      float v = acc[i][j] + bias[cc];
      if (colscale) v *= colscale[cc] * csmul;
      if (rowscale) v *= rowscale[rr];
      if (TRANS_OUT) {
        C[((size_t)(rr >> 8) * RR + cc) * MM + (rr & 255)] = v;
      } else {
        C[(size_t)rr * RR + cc] = v;
      }
    }
  }
}

__global__ __launch_bounds__(256) void k_gemm_skinny(
    const float* __restrict__ A, const float* __restrict__ W,
    const float* __restrict__ bias, float* __restrict__ C) {
  __shared__ float As[32][132];
  gemm_skinny_body<false>(A, W, bias, nullptr, 1.f, nullptr, C,
                          blockIdx.x * 32, As);
}

// pt1 (cols scaled by p_w*0.1) and ps1T (rows scaled by ms1, transposed out)
// in ONE launch: 128 blocks each.
__global__ __launch_bounds__(256) void k_gemm_pair(
    const float* __restrict__ mv1, const float* __restrict__ pUt_w,
    const float* __restrict__ pUt_b, const float* __restrict__ p_w,
    const float* __restrict__ pUs_w, const float* __restrict__ pUs_b,
    const float* __restrict__ ms1, float* __restrict__ pt1,
    float* __restrict__ ps1T) {
  __shared__ float As[32][132];
  if (blockIdx.x < 128) {
    gemm_skinny_body<false>(mv1, pUt_w, pUt_b, p_w, 0.1f, nullptr, pt1,
                            blockIdx.x * 32, As);
  } else {
    gemm_skinny_body<true>(mv1, pUs_w, pUs_b, nullptr, 1.f, ms1, ps1T,
                           (blockIdx.x - 128) * 32, As);
  }
}

// ---------------------------------------------------------------------------
// scores[b,m,j] = pt0[m,:]·ps[b,j,:]   (K=64). Tile 64m x 64j.
// ---------------------------------------------------------------------------
__global__ __launch_bounds__(256) void k_scores(
    const float* __restrict__ pt0, const float* __restrict__ ps,
    float* __restrict__ scores) {
  int b = blockIdx.z;
  int m0 = blockIdx.y * 64;
  int j0 = blockIdx.x * 64;
  __shared__ float Pt[64][65];
  __shared__ float Ps[64][65];
  int tid = threadIdx.x;
  int ty = tid >> 4, tx = tid & 15;
#pragma unroll
  for (int i = 0; i < 4; ++i) {
    int idx4 = i * 256 + tid;
    int r = idx4 >> 4;
    int c = (idx4 & 15) << 2;
    float4 vp = *reinterpret_cast<const float4*>(&pt0[(size_t)(m0 + r) * RR + c]);
    Pt[r][c] = vp.x; Pt[r][c + 1] = vp.y; Pt[r][c + 2] = vp.z; Pt[r][c + 3] = vp.w;
    float4 vs = *reinterpret_cast<const float4*>(
        &ps[((size_t)b * SS + j0 + r) * RR + c]);
    Ps[r][c] = vs.x; Ps[r][c + 1] = vs.y; Ps[r][c + 2] = vs.z; Ps[r][c + 3] = vs.w;
  }
  __syncthreads();
  float acc[4][4] = {};
#pragma unroll
  for (int k = 0; k < 64; ++k) {
    float a0 = Pt[ty * 4 + 0][k], a1 = Pt[ty * 4 + 1][k];
    float a2 = Pt[ty * 4 + 2][k], a3 = Pt[ty * 4 + 3][k];
    float b0 = Ps[tx * 4 + 0][k], b1 = Ps[tx * 4 + 1][k];
    float b2 = Ps[tx * 4 + 2][k], b3 = Ps[tx * 4 + 3][k];
    acc[0][0] += a0 * b0; acc[0][1] += a0 * b1; acc[0][2] += a0 * b2; acc[0][3] += a0 * b3;
    acc[1][0] += a1 * b0; acc[1][1] += a1 * b1; acc[1][2] += a1 * b2; acc[1][3] += a1 * b3;
    acc[2][0] += a2 * b0; acc[2][1] += a2 * b1; acc[2][2] += a2 * b2; acc[2][3] += a2 * b3;
    acc[3][0] += a3 * b0; acc[3][1] += a3 * b1; acc[3][2] += a3 * b2; acc[3][3] += a3 * b3;
  }
  float* obase = scores + (size_t)b * MM * SS;
#pragma unroll
  for (int i = 0; i < 4; ++i) {
#pragma unroll
    for (int j = 0; j < 4; ++j) {
      obase[(size_t)(m0 + ty * 4 + i) * SS + j0 + tx * 4 + j] = acc[i][j];
    }
  }
}

// ---------------------------------------------------------------------------
// One WAVE per (b,m) row. Score row staged in LDS. Ballot binary-search
// threshold with cnt==16 early exit; compact; signed-abs-softmax; gather
// token rows; LN -> mv1. XCD b-affinity swizzle.
// ---------------------------------------------------------------------------
__global__ __launch_bounds__(256) void k_write(
    const float* __restrict__ scores, const float* __restrict__ token_val,
    const float* __restrict__ token_state, const float* __restrict__ mv0,
    const float* __restrict__ ms0, const float* __restrict__ ln_g,
    const float* __restrict__ ln_b, float* __restrict__ mv1,
    float* __restrict__ ms_w) {
  int t = threadIdx.x;
  int wave = t >> 6, lane = t & 63;
  int i = blockIdx.x;                 // 0..1023
  int slot = i >> 3;                  // 0..127
  int b = 2 * (i & 7) + (slot >> 6);  // two b per xcd
  int m = (slot & 63) * 4 + wave;
  int row = b * MM + m;
  __shared__ float srl[4][SS];        // 8KB per wave
  __shared__ int selj_sh[4][KK];
  float4* srl4 = reinterpret_cast<float4*>(&srl[wave][0]);
  const float* srow = scores + (size_t)row * SS;
  unsigned maxa = 0u;
#pragma unroll
  for (int ch = 0; ch < 8; ++ch) {
    float4 q = *reinterpret_cast<const float4*>(srow + (ch * 64 + lane) * 4);
    srl4[ch * 64 + lane] = q;
    maxa = max(maxa, __float_as_uint(q.x) & 0x7fffffffu);
    maxa = max(maxa, __float_as_uint(q.y) & 0x7fffffffu);
    maxa = max(maxa, __float_as_uint(q.z) & 0x7fffffffu);
    maxa = max(maxa, __float_as_uint(q.w) & 0x7fffffffu);
  }
#pragma unroll
  for (int off = 32; off > 0; off >>= 1)
    maxa = max(maxa, (unsigned)__shfl_xor((int)maxa, off));
  unsigned lo = 0u, hi = maxa, thr = 0u;
  bool early = false;
  while (lo < hi) {
    unsigned mid = lo + ((hi - lo + 1u) >> 1);
    int cnt = 0;
#pragma unroll
    for (int ch = 0; ch < 8; ++ch) {
      float4 q = srl4[ch * 64 + lane];
      cnt += __popcll(__ballot((__float_as_uint(q.x) & 0x7fffffffu) >= mid));
      cnt += __popcll(__ballot((__float_as_uint(q.y) & 0x7fffffffu) >= mid));
      cnt += __popcll(__ballot((__float_as_uint(q.z) & 0x7fffffffu) >= mid));
      cnt += __popcll(__ballot((__float_as_uint(q.w) & 0x7fffffffu) >= mid));
    }
    if (cnt == KK) { thr = mid; early = true; break; }
    if (cnt > KK) lo = mid; else hi = mid - 1u;
  }
  if (!early) thr = lo;
  unsigned long long ltmask = (1ull << lane) - 1ull;
  int s = 0;
  unsigned tiemask = 0u;
#pragma unroll
  for (int ch = 0; ch < 8; ++ch) {
    float4 q = srl4[ch * 64 + lane];
    unsigned a4[4] = {__float_as_uint(q.x) & 0x7fffffffu,
                      __float_as_uint(q.y) & 0x7fffffffu,
                      __float_as_uint(q.z) & 0x7fffffffu,
                      __float_as_uint(q.w) & 0x7fffffffu};
#pragma unroll
    for (int cc = 0; cc < 4; ++cc) {
      bool sg = early ? (a4[cc] >= thr) : (a4[cc] > thr);
      unsigned long long mk = __ballot(sg);
      if (sg) selj_sh[wave][s + __popcll(mk & ltmask)] = ch * 256 + lane * 4 + cc;
      s += __popcll(mk);
      if (!early && a4[cc] == thr) tiemask |= 1u << (ch * 4 + cc);
    }
  }
  int taken = s;
  while (taken < KK) {   // rare: fill ties by ascending index
    int myj = 0x7fffffff;
#pragma unroll
    for (int c = 0; c < 32; ++c)
      if ((tiemask >> c) & 1u) {
        int j = (c >> 2) * 256 + lane * 4 + (c & 3);
        myj = min(myj, j);
      }
    int wj = myj;
#pragma unroll
    for (int off = 32; off > 0; off >>= 1) wj = min(wj, __shfl_xor(wj, off));
    if (wj == 0x7fffffff) break;
    if (((wj >> 2) & 63) == lane) tiemask &= ~(1u << (((wj >> 8) << 2) | (wj & 3)));
    if (lane == 0) selj_sh[wave][taken] = wj;
    ++taken;
  }
  int js[KK];
  float es[KK];
#pragma unroll
  for (int k = 0; k < KK; ++k) {
    js[k] = selj_sh[wave][k];
    es[k] = srl[wave][js[k]];
  }
  float mx = 0.f;
#pragma unroll
  for (int k = 0; k < KK; ++k) mx = fmaxf(mx, fabsf(es[k]));
  float ssum = 0.f;
#pragma unroll
  for (int k = 0; k < KK; ++k) {
    float ex = expf(fabsf(es[k]) - mx);
    ssum += ex;
    es[k] = sgnf(es[k]) * ex;
  }
  float inv = 1.f / ssum;
  int dbase = lane * 8;
  const float* m0row = mv0 + m * DD + dbase;
  float4 a0 = *reinterpret_cast<const float4*>(m0row);
  float4 a1 = *reinterpret_cast<const float4*>(m0row + 4);
  float acc[8] = {a0.x, a0.y, a0.z, a0.w, a1.x, a1.y, a1.z, a1.w};
  float stacc = 0.f;
#pragma unroll
  for (int k = 0; k < KK; ++k) {
    float e = es[k] * inv;
    const float* tv = token_val + ((size_t)b * SS + js[k]) * DD + dbase;
    float4 u0 = *reinterpret_cast<const float4*>(tv);
    float4 u1 = *reinterpret_cast<const float4*>(tv + 4);
    acc[0] += e * u0.x; acc[1] += e * u0.y; acc[2] += e * u0.z; acc[3] += e * u0.w;
    acc[4] += e * u1.x; acc[5] += e * u1.y; acc[6] += e * u1.z; acc[7] += e * u1.w;
    stacc += e * token_state[(size_t)b * SS + js[k]];
  }
  if (lane == 0) ms_w[row] = ms0[m] + stacc;
  float s1 = 0.f, s2 = 0.f;
#pragma unroll
  for (int c = 0; c < 8; ++c) { s1 += acc[c]; s2 += acc[c] * acc[c]; }
  s1 = wave_sum(s1);
  s2 = wave_sum(s2);
  float mean = s1 * (1.0f / DD);
  float var = s2 * (1.0f / DD) - mean * mean;
  float rs = rsqrtf(var + 1e-5f);
  float4 g0 = *reinterpret_cast<const float4*>(ln_g + dbase);
  float4 g1 = *reinterpret_cast<const float4*>(ln_g + dbase + 4);
  float4 b0v = *reinterpret_cast<const float4*>(ln_b + dbase);
  float4 b1v = *reinterpret_cast<const float4*>(ln_b + dbase + 4);
  float4 o0, o1;
  o0.x = (acc[0] - mean) * rs * g0.x + b0v.x;
  o0.y = (acc[1] - mean) * rs * g0.y + b0v.y;
  o0.z = (acc[2] - mean) * rs * g0.z + b0v.z;
  o0.w = (acc[3] - mean) * rs * g0.w + b0v.w;
  o1.x = (acc[4] - mean) * rs * g1.x + b1v.x;
  o1.y = (acc[5] - mean) * rs * g1.y + b1v.y;
  o1.z = (acc[6] - mean) * rs * g1.z + b1v.z;
  o1.w = (acc[7] - mean) * rs * g1.w + b1v.w;
  float* orow = mv1 + (size_t)row * DD + dbase;
  *reinterpret_cast<float4*>(orow) = o0;
  *reinterpret_cast<float4*>(orow + 4) = o1;
}

// ---------------------------------------------------------------------------
// One WAVE per (b,m): pscores[j] = pt1[row,:]·ps1T[b,:,j] (ms1 folded in);
// ballot-threshold top-16 -> edges -> gather mv1 -> residual -> LN -> out.
// ---------------------------------------------------------------------------
__global__ __launch_bounds__(256, 4) void k_prop(
    const float* __restrict__ pt1, const float* __restrict__ ps1T,
    const float* __restrict__ mv1, const float* __restrict__ ln_g,
    const float* __restrict__ ln_b, float* __restrict__ out) {
  int t = threadIdx.x;
  int wave = t >> 6, lane = t & 63;
  int row = blockIdx.x * 4 + wave;          // row = b*MM + m
  int b = row >> 8, m = row & 255;
  __shared__ int selj_sh[4][KK];
  __shared__ float selv_sh[4][KK];
  float ptval = pt1[(size_t)row * RR + lane];
  const float* pB = ps1T + (size_t)b * RR * MM + lane * 4;
  float sc[4] = {0.f, 0.f, 0.f, 0.f};
#pragma unroll 8
  for (int r = 0; r < RR; ++r) {
    float w = __shfl(ptval, r);
    float4 pv = *reinterpret_cast<const float4*>(pB + r * MM);
    sc[0] += w * pv.x; sc[1] += w * pv.y; sc[2] += w * pv.z; sc[3] += w * pv.w;
  }
  int jbase = lane * 4;
  unsigned au[4];
#pragma unroll
  for (int c = 0; c < 4; ++c) au[c] = __float_as_uint(sc[c]) & 0x7fffffffu;
  unsigned lo = 0u, hi = 0x7f800000u, thr = 0u;
  bool early = false;
  while (lo < hi) {
    unsigned mid = lo + ((hi - lo + 1u) >> 1);
    int cnt = 0;
#pragma unroll
    for (int c = 0; c < 4; ++c) cnt += __popcll(__ballot(au[c] >= mid));
    if (cnt == KK) { thr = mid; early = true; break; }
    if (cnt > KK) lo = mid; else hi = mid - 1u;
  }
  if (!early) thr = lo;
  unsigned long long ltmask = (1ull << lane) - 1ull;
  int s = 0;
  unsigned tiemask = 0u;
#pragma unroll
  for (int c = 0; c < 4; ++c) {
    bool sg = early ? (au[c] >= thr) : (au[c] > thr);
    unsigned long long mk = __ballot(sg);
    if (sg) {
      int slot = s + __popcll(mk & ltmask);
      selj_sh[wave][slot] = jbase + c;
      selv_sh[wave][slot] = sc[c];
    }
    s += __popcll(mk);
    if (!early && au[c] == thr) tiemask |= 1u << c;
  }
  int taken = s;
  while (taken < KK) {
    int myj = 0x7fffffff;
#pragma unroll
    for (int c = 0; c < 4; ++c)
      if ((tiemask >> c) & 1u) myj = min(myj, jbase + c);
    int wj = myj;
#pragma unroll
    for (int off = 32; off > 0; off >>= 1) wj = min(wj, __shfl_xor(wj, off));
    if (wj == 0x7fffffff) break;
    if (wj >= jbase && wj < jbase + 4) {
      tiemask &= ~(1u << (wj - jbase));
      selv_sh[wave][taken] = sc[wj - jbase];
      if (lane == (wj >> 2)) selj_sh[wave][taken] = wj;
    }
    ++taken;
  }
  int js[KK];
  float es[KK];
#pragma unroll
  for (int k = 0; k < KK; ++k) { js[k] = selj_sh[wave][k]; es[k] = selv_sh[wave][k]; }
  float mx = 0.f;
#pragma unroll
  for (int k = 0; k < KK; ++k) mx = fmaxf(mx, fabsf(es[k]));
  float ssum = 0.f;
#pragma unroll
  for (int k = 0; k < KK; ++k) {
    float ex = expf(fabsf(es[k]) - mx);
    ssum += ex;
    es[k] = sgnf(es[k]) * ex;
  }
  float inv = 1.f / ssum;
  int dbase = lane * 8;
  const float* mrow = mv1 + (size_t)row * DD + dbase;
  float4 a0 = *reinterpret_cast<const float4*>(mrow);
  float4 a1 = *reinterpret_cast<const float4*>(mrow + 4);
  float acc[8] = {a0.x, a0.y, a0.z, a0.w, a1.x, a1.y, a1.z, a1.w};
#pragma unroll
  for (int k = 0; k < KK; ++k) {
    float e = es[k] * inv;
    const float* pv = mv1 + ((size_t)b * MM + js[k]) * DD + dbase;
    float4 u0 = *reinterpret_cast<const float4*>(pv);
    float4 u1 = *reinterpret_cast<const float4*>(pv + 4);
    acc[0] += e * u0.x; acc[1] += e * u0.y; acc[2] += e * u0.z; acc[3] += e * u0.w;
    acc[4] += e * u1.x; acc[5] += e * u1.y; acc[6] += e * u1.z; acc[7] += e * u1.w;
  }
  float s1 = 0.f, s2 = 0.f;
#pragma unroll
  for (int c = 0; c < 8; ++c) { s1 += acc[c]; s2 += acc[c] * acc[c]; }
  s1 = wave_sum(s1);
  s2 = wave_sum(s2);
  float mean = s1 * (1.0f / DD);
  float var = s2 * (1.0f / DD) - mean * mean;
  float rs = rsqrtf(var + 1e-5f);
  float4 g0 = *reinterpret_cast<const float4*>(ln_g + dbase);
  float4 g1 = *reinterpret_cast<const float4*>(ln_g + dbase + 4);
  float4 b0v = *reinterpret_cast<const float4*>(ln_b + dbase);
  float4 b1v = *reinterpret_cast<const float4*>(ln_b + dbase + 4);
  float4 o0, o1;
  o0.x = (acc[0] - mean) * rs * g0.x + b0v.x;
  o0.y = (acc[1] - mean) * rs * g0.y + b0v.y;
  o0.z = (acc[2] - mean) * rs * g0.z + b0v.z;
  o0.w = (acc[3] - mean) * rs * g0.w + b0v.w;
  o1.x = (acc[4] - mean) * rs * g1.x + b1v.x;
  o1.y = (acc[5] - mean) * rs * g1.y + b1v.y;
  o1.z = (acc[6] - mean) * rs * g1.z + b1v.z;
  o1.w = (acc[7] - mean) * rs * g1.w + b1v.w;
  float* orow = out + (size_t)row * DD + dbase;
  *reinterpret_cast<float4*>(orow) = o0;
  *reinterpret_cast<float4*>(orow + 4) = o1;
}

extern "C" void kernel_launch(void* const* d_in, const int* in_sizes, int n_in,
                              void* d_out, int out_size, void* d_ws,
                              size_t ws_size, hipStream_t stream) {
  const float* token_val = (const float*)d_in[0];
  const float* token_state = (const float*)d_in[1];
  const float* init_state = (const float*)d_in[2];
  const float* init_val = (const float*)d_in[3];
  const float* rUs_w = (const float*)d_in[4];
  const float* rUs_b = (const float*)d_in[5];
  const float* rUt_w = (const float*)d_in[6];
  const float* rUt_b = (const float*)d_in[7];
  const float* r_w = (const float*)d_in[8];
  const float* pUs_w = (const float*)d_in[9];
  const float* pUs_b = (const float*)d_in[10];
  const float* pUt_w = (const float*)d_in[11];
  const float* pUt_b = (const float*)d_in[12];
  const float* p_w = (const float*)d_in[13];
  const float* ln_g = (const float*)d_in[14];
  const float* ln_b = (const float*)d_in[15];
  float* out = (float*)d_out;

  float* ws = (float*)d_ws;
  float* mv0 = ws;    ws += MM * DD;
  float* pt0 = ws;    ws += MM * RR;
  float* ms0 = ws;    ws += MM;
  float* ps = ws;     ws += (size_t)BB * SS * RR;
  float* scores = ws; ws += (size_t)BB * MM * SS;
  float* mv1 = ws;    ws += (size_t)BB * MM * DD;
  float* ms_w = ws;   ws += BB * MM;
  float* ms1 = ws;    ws += BB * MM;
  float* pt1 = ws;    ws += (size_t)BB * MM * RR;
  float* ps1T = ws;   ws += (size_t)BB * RR * MM;

  k_init<<<MM, 256, 0, stream>>>(init_val, ln_g, ln_b, rUt_w, rUt_b, r_w, mv0, pt0);
  k_state_softmax<<<1, 256, 0, stream>>>(init_state, ms0);
  k_gemm_skinny<<<(BB * SS) / 32, 256, 0, stream>>>(token_val, rUs_w, rUs_b, ps);
  dim3 gs(SS / 64, MM / 64, BB);
  k_scores<<<gs, 256, 0, stream>>>(pt0, ps, scores);
  k_write<<<(BB * MM) / 4, 256, 0, stream>>>(scores, token_val, token_state,
                                             mv0, ms0, ln_g, ln_b, mv1, ms_w);
  k_state_softmax<<<BB, 256, 0, stream>>>(ms_w, ms1);
  k_gemm_pair<<<256, 256, 0, stream>>>(mv1, pUt_w, pUt_b, p_w, pUs_w, pUs_b,
                                       ms1, pt1, ps1T);
  k_prop<<<(BB * MM) / 4, 256, 0, stream>>>(pt1, ps1T, mv1, ln_g, ln_b, out);
}

// Round 6
// 162.458 us; speedup vs baseline: 2.3501x; 1.2171x over previous
//
#include <hip/hip_runtime.h>
#include <hip/hip_bf16.h>
#include <math.h>

#define BB 16
#define SS 2048
#define DD 512
#define MM 256
#define RR 64
#define KK 16
#define GPAD 68  // LDS row pad: 272B stride = 16B-aligned, conflict-free reads

__device__ __forceinline__ float wave_sum(float v) {
#pragma unroll
  for (int off = 32; off > 0; off >>= 1) v += __shfl_xor(v, off);
  return v;
}

__device__ __forceinline__ float sgnf(float v) {
  return (v > 0.f) ? 1.f : ((v < 0.f) ? -1.f : 0.f);
}

// ---------------------------------------------------------------------------
// LN(init_val) -> mv0 [M,D]; pt0[m,r] = (mv0[m]·rUt_w[:,r] + rUt_b[r])*r_w[r]*0.1
// ---------------------------------------------------------------------------
__global__ __launch_bounds__(256) void k_init(
    const float* __restrict__ init_val, const float* __restrict__ ln_g,
    const float* __restrict__ ln_b, const float* __restrict__ rUt_w,
    const float* __restrict__ rUt_b, const float* __restrict__ r_w,
    float* __restrict__ mv0, float* __restrict__ pt0) {
  int m = blockIdx.x, t = threadIdx.x;
  __shared__ float row[DD];
  __shared__ float red[8];
  float x0 = init_val[m * DD + t];
  float x1 = init_val[m * DD + t + 256];
  float s = wave_sum(x0 + x1);
  float sq = wave_sum(x0 * x0 + x1 * x1);
  if ((t & 63) == 0) { red[t >> 6] = s; red[4 + (t >> 6)] = sq; }
  __syncthreads();
  float mean = (red[0] + red[1] + red[2] + red[3]) * (1.0f / DD);
  float var = (red[4] + red[5] + red[6] + red[7]) * (1.0f / DD) - mean * mean;
  float rs = rsqrtf(var + 1e-5f);
  float n0 = (x0 - mean) * rs * ln_g[t] + ln_b[t];
  float n1 = (x1 - mean) * rs * ln_g[t + 256] + ln_b[t + 256];
  mv0[m * DD + t] = n0;
  mv0[m * DD + t + 256] = n1;
  row[t] = n0;
  row[t + 256] = n1;
  __syncthreads();
  if (t < RR) {
    float acc = rUt_b[t];
    for (int d = 0; d < DD; ++d) acc += row[d] * rUt_w[d * RR + t];
    pt0[m * RR + t] = acc * r_w[t] * 0.1f;
  }
}

// ---------------------------------------------------------------------------
// signed_softmax_state over 256 elements per block-row
// ---------------------------------------------------------------------------
__global__ __launch_bounds__(256) void k_state_softmax(
    const float* __restrict__ in, float* __restrict__ out) {
  int b = blockIdx.x, t = threadIdx.x;
  __shared__ float red[4];
  float v = in[b * MM + t];
  float a = fabsf(v);
  float mx = a;
#pragma unroll
  for (int off = 32; off > 0; off >>= 1) mx = fmaxf(mx, __shfl_xor(mx, off));
  if ((t & 63) == 0) red[t >> 6] = mx;
  __syncthreads();
  mx = fmaxf(fmaxf(red[0], red[1]), fmaxf(red[2], red[3]));
  __syncthreads();
  float e = expf(a - mx);
  float ssum = wave_sum(e);
  if ((t & 63) == 0) red[t >> 6] = ssum;
  __syncthreads();
  ssum = red[0] + red[1] + red[2] + red[3];
  out[b * MM + t] = sgnf(v) * e / ssum * 4.0f;
}

// ---------------------------------------------------------------------------
// Skinny GEMM: C[rows,64] = A[rows,512] @ W[512,64] + bias.
// 64-row tile, 256 threads (16x16), micro 4x4, K-chunk 32.
// A staged TRANSPOSED Ast[k][row] (pad 68): micro-tile A read is one
// broadcast ds_read_b128; W staged Ws[k][col] (pad 68): 2-way-free b128.
// ---------------------------------------------------------------------------
template <bool TRANS_OUT>
__device__ __forceinline__ void gemm_body(
    const float* __restrict__ A, const float* __restrict__ W,
    const float* __restrict__ bias, const float* __restrict__ colscale,
    float csmul, const float* __restrict__ rowscale, float* __restrict__ C,
    int row0, float (*Ast)[GPAD], float (*Ws)[GPAD]) {
  int tid = threadIdx.x;
  int ty = tid >> 4, tx = tid & 15;
  float acc[4][4] = {};
  for (int kc = 0; kc < DD; kc += 32) {
#pragma unroll
    for (int i = 0; i < 2; ++i) {
      int s4 = i * 256 + tid;        // 0..511 : A tile 64r x 8 f4
      int r = s4 >> 3;
      int k4 = s4 & 7;
      float4 v = *reinterpret_cast<const float4*>(
          &A[(size_t)(row0 + r) * DD + kc + k4 * 4]);
      Ast[k4 * 4 + 0][r] = v.x;
      Ast[k4 * 4 + 1][r] = v.y;
      Ast[k4 * 4 + 2][r] = v.z;
      Ast[k4 * 4 + 3][r] = v.w;
    }
#pragma unroll
    for (int i = 0; i < 2; ++i) {
      int s4 = i * 256 + tid;        // 0..511 : W tile 32k x 16 f4
      int r = s4 >> 4;
      int c4 = s4 & 15;
      float4 v = *reinterpret_cast<const float4*>(
          &W[(size_t)(kc + r) * RR + c4 * 4]);
      *reinterpret_cast<float4*>(&Ws[r][c4 * 4]) = v;
    }
    __syncthreads();
#pragma unroll
    for (int k = 0; k < 32; ++k) {
      float4 a4 = *reinterpret_cast<const float4*>(&Ast[k][ty * 4]);
      float4 w4 = *reinterpret_cast<const float4*>(&Ws[k][tx * 4]);
      acc[0][0] += a4.x * w4.x; acc[0][1] += a4.x * w4.y;
      acc[0][2] += a4.x * w4.z; acc[0][3] += a4.x * w4.w;
      acc[1][0] += a4.y * w4.x; acc[1][1] += a4.y * w4.y;
      acc[1][2] += a4.y * w4.z; acc[1][3] += a4.y * w4.w;
      acc[2][0] += a4.z * w4.x; acc[2][1] += a4.z * w4.y;
      acc[2][2] += a4.z * w4.z; acc[2][3] += a4.z * w4.w;
      acc[3][0] += a4.w * w4.x; acc[3][1] += a4.w * w4.y;
      acc[3][2] += a4.w * w4.z; acc[3][3] += a4.w * w4.w;
    }
    __syncthreads();
  }
#pragma unroll
  for (int i = 0; i < 4; ++i) {
    int rr = row0 + ty * 4 + i;
    float rsc = rowscale ? rowscale[rr] : 1.f;
    if (TRANS_OUT) {
#pragma unroll
      for (int j = 0; j < 4; ++j) {
        int cc = tx * 4 + j;
        float v = acc[i][j] + bias[cc];
        if (colscale) v *= colscale[cc] * csmul;
        v *= rsc;
        C[((size_t)(rr >> 8) * RR + cc) * MM + (rr & 255)] = v;
      }
    } else {
      float4 o;
      float b0 = bias[tx * 4], b1 = bias[tx * 4 + 1];
      float b2 = bias[tx * 4 + 2], b3 = bias[tx * 4 + 3];
      o.x = acc[i][0] + b0; o.y = acc[i][1] + b1;
      o.z = acc[i][2] + b2; o.w = acc[i][3] + b3;
      if (colscale) {
        o.x *= colscale[tx * 4] * csmul; o.y *= colscale[tx * 4 + 1] * csmul;
        o.z *= colscale[tx * 4 + 2] * csmul; o.w *= colscale[tx * 4 + 3] * csmul;
      }
      o.x *= rsc; o.y *= rsc; o.z *= rsc; o.w *= rsc;
      *reinterpret_cast<float4*>(&C[(size_t)rr * RR + tx * 4]) = o;
    }
  }
}

__global__ __launch_bounds__(256) void k_gemm_skinny(
    const float* __restrict__ A, const float* __restrict__ W,
    const float* __restrict__ bias, float* __restrict__ C) {
  __shared__ float Ast[32][GPAD];
  __shared__ float Ws[32][GPAD];
  gemm_body<false>(A, W, bias, nullptr, 1.f, nullptr, C, blockIdx.x * 64,
                   Ast, Ws);
}

// pt1 (cols scaled by p_w*0.1) and ps1T (rows scaled by ms1, transposed out)
// in ONE launch: 64 blocks each.
__global__ __launch_bounds__(256) void k_gemm_pair(
    const float* __restrict__ mv1, const float* __restrict__ pUt_w,
    const float* __restrict__ pUt_b, const float* __restrict__ p_w,
    const float* __restrict__ pUs_w, const float* __restrict__ pUs_b,
    const float* __restrict__ ms1, float* __restrict__ pt1,
    float* __restrict__ ps1T) {
  __shared__ float Ast[32][GPAD];
  __shared__ float Ws[32][GPAD];
  if (blockIdx.x < 64) {
    gemm_body<false>(mv1, pUt_w, pUt_b, p_w, 0.1f, nullptr, pt1,
                     blockIdx.x * 64, Ast, Ws);
  } else {
    gemm_body<true>(mv1, pUs_w, pUs_b, nullptr, 1.f, ms1, ps1T,
                    (blockIdx.x - 64) * 64, Ast, Ws);
  }
}

// ---------------------------------------------------------------------------
// scores[b,m,j] = pt0[m,:]·ps[b,j,:]   (K=64). Tile 64m x 64j.
// ---------------------------------------------------------------------------
__global__ __launch_bounds__(256) void k_scores(
    const float* __restrict__ pt0, const float* __restrict__ ps,
    float* __restrict__ scores) {
  int b = blockIdx.z;
  int m0 = blockIdx.y * 64;
  int j0 = blockIdx.x * 64;
  __shared__ float Pt[64][65];
  __shared__ float Ps[64][65];
  int tid = threadIdx.x;
  int ty = tid >> 4, tx = tid & 15;
#pragma unroll
  for (int i = 0; i < 4; ++i) {
    int idx4 = i * 256 + tid;
    int r = idx4 >> 4;
    int c = (idx4 & 15) << 2;
    float4 vp = *reinterpret_cast<const float4*>(&pt0[(size_t)(m0 + r) * RR + c]);
    Pt[r][c] = vp.x; Pt[r][c + 1] = vp.y; Pt[r][c + 2] = vp.z; Pt[r][c + 3] = vp.w;
    float4 vs = *reinterpret_cast<const float4*>(
        &ps[((size_t)b * SS + j0 + r) * RR + c]);
    Ps[r][c] = vs.x; Ps[r][c + 1] = vs.y; Ps[r][c + 2] = vs.z; Ps[r][c + 3] = vs.w;
  }
  __syncthreads();
  float acc[4][4] = {};
#pragma unroll
  for (int k = 0; k < 64; ++k) {
    float a0 = Pt[ty * 4 + 0][k], a1 = Pt[ty * 4 + 1][k];
    float a2 = Pt[ty * 4 + 2][k], a3 = Pt[ty * 4 + 3][k];
    float b0 = Ps[tx * 4 + 0][k], b1 = Ps[tx * 4 + 1][k];
    float b2 = Ps[tx * 4 + 2][k], b3 = Ps[tx * 4 + 3][k];
    acc[0][0] += a0 * b0; acc[0][1] += a0 * b1; acc[0][2] += a0 * b2; acc[0][3] += a0 * b3;
    acc[1][0] += a1 * b0; acc[1][1] += a1 * b1; acc[1][2] += a1 * b2; acc[1][3] += a1 * b3;
    acc[2][0] += a2 * b0; acc[2][1] += a2 * b1; acc[2][2] += a2 * b2; acc[2][3] += a2 * b3;
    acc[3][0] += a3 * b0; acc[3][1] += a3 * b1; acc[3][2] += a3 * b2; acc[3][3] += a3 * b3;
  }
  float* obase = scores + (size_t)b * MM * SS;
#pragma unroll
  for (int i = 0; i < 4; ++i) {
#pragma unroll
    for (int j = 0; j < 4; ++j) {
      obase[(size_t)(m0 + ty * 4 + i) * SS + j0 + tx * 4 + j] = acc[i][j];
    }
  }
}

// ---------------------------------------------------------------------------
// One WAVE per (b,m) row. Score row staged in LDS. Ballot binary-search
// threshold with cnt==16 early exit; compact; signed-abs-softmax; gather
// token rows; LN -> mv1. XCD b-affinity swizzle.
// ---------------------------------------------------------------------------
__global__ __launch_bounds__(256) void k_write(
    const float* __restrict__ scores, const float* __restrict__ token_val,
    const float* __restrict__ token_state, const float* __restrict__ mv0,
    const float* __restrict__ ms0, const float* __restrict__ ln_g,
    const float* __restrict__ ln_b, float* __restrict__ mv1,
    float* __restrict__ ms_w) {
  int t = threadIdx.x;
  int wave = t >> 6, lane = t & 63;
  int i = blockIdx.x;                 // 0..1023
  int slot = i >> 3;                  // 0..127
  int b = 2 * (i & 7) + (slot >> 6);  // two b per xcd
  int m = (slot & 63) * 4 + wave;
  int row = b * MM + m;
  __shared__ float srl[4][SS];        // 8KB per wave
  __shared__ int selj_sh[4][KK];
  float4* srl4 = reinterpret_cast<float4*>(&srl[wave][0]);
  const float* srow = scores + (size_t)row * SS;
  unsigned maxa = 0u;
#pragma unroll
  for (int ch = 0; ch < 8; ++ch) {
    float4 q = *reinterpret_cast<const float4*>(srow + (ch * 64 + lane) * 4);
    srl4[ch * 64 + lane] = q;
    maxa = max(maxa, __float_as_uint(q.x) & 0x7fffffffu);
    maxa = max(maxa, __float_as_uint(q.y) & 0x7fffffffu);
    maxa = max(maxa, __float_as_uint(q.z) & 0x7fffffffu);
    maxa = max(maxa, __float_as_uint(q.w) & 0x7fffffffu);
  }
#pragma unroll
  for (int off = 32; off > 0; off >>= 1)
    maxa = max(maxa, (unsigned)__shfl_xor((int)maxa, off));
  unsigned lo = 0u, hi = maxa, thr = 0u;
  bool early = false;
  while (lo < hi) {
    unsigned mid = lo + ((hi - lo + 1u) >> 1);
    int cnt = 0;
#pragma unroll
    for (int ch = 0; ch < 8; ++ch) {
      float4 q = srl4[ch * 64 + lane];
      cnt += __popcll(__ballot((__float_as_uint(q.x) & 0x7fffffffu) >= mid));
      cnt += __popcll(__ballot((__float_as_uint(q.y) & 0x7fffffffu) >= mid));
      cnt += __popcll(__ballot((__float_as_uint(q.z) & 0x7fffffffu) >= mid));
      cnt += __popcll(__ballot((__float_as_uint(q.w) & 0x7fffffffu) >= mid));
    }
    if (cnt == KK) { thr = mid; early = true; break; }
    if (cnt > KK) lo = mid; else hi = mid - 1u;
  }
  if (!early) thr = lo;
  unsigned long long ltmask = (1ull << lane) - 1ull;
  int s = 0;
  unsigned tiemask = 0u;
#pragma unroll
  for (int ch = 0; ch < 8; ++ch) {
    float4 q = srl4[ch * 64 + lane];
    unsigned a4[4] = {__float_as_uint(q.x) & 0x7fffffffu,
                      __float_as_uint(q.y) & 0x7fffffffu,
                      __float_as_uint(q.z) & 0x7fffffffu,
                      __float_as_uint(q.w) & 0x7fffffffu};
#pragma unroll
    for (int cc = 0; cc < 4; ++cc) {
      bool sg = early ? (a4[cc] >= thr) : (a4[cc] > thr);
      unsigned long long mk = __ballot(sg);
      if (sg) selj_sh[wave][s + __popcll(mk & ltmask)] = ch * 256 + lane * 4 + cc;
      s += __popcll(mk);
      if (!early && a4[cc] == thr) tiemask |= 1u << (ch * 4 + cc);
    }
  }
  int taken = s;
  while (taken < KK) {   // rare: fill ties by ascending index
    int myj = 0x7fffffff;
#pragma unroll
    for (int c = 0; c < 32; ++c)
      if ((tiemask >> c) & 1u) {
        int j = (c >> 2) * 256 + lane * 4 + (c & 3);
        myj = min(myj, j);
      }
    int wj = myj;
#pragma unroll
    for (int off = 32; off > 0; off >>= 1) wj = min(wj, __shfl_xor(wj, off));
    if (wj == 0x7fffffff) break;
    if (((wj >> 2) & 63) == lane) tiemask &= ~(1u << (((wj >> 8) << 2) | (wj & 3)));
    if (lane == 0) selj_sh[wave][taken] = wj;
    ++taken;
  }
  int js[KK];
  float es[KK];
#pragma unroll
  for (int k = 0; k < KK; ++k) {
    js[k] = selj_sh[wave][k];
    es[k] = srl[wave][js[k]];
  }
  float mx = 0.f;
#pragma unroll
  for (int k = 0; k < KK; ++k) mx = fmaxf(mx, fabsf(es[k]));
  float ssum = 0.f;
#pragma unroll
  for (int k = 0; k < KK; ++k) {
    float ex = expf(fabsf(es[k]) - mx);
    ssum += ex;
    es[k] = sgnf(es[k]) * ex;
  }
  float inv = 1.f / ssum;
  int dbase = lane * 8;
  const float* m0row = mv0 + m * DD + dbase;
  float4 a0 = *reinterpret_cast<const float4*>(m0row);
  float4 a1 = *reinterpret_cast<const float4*>(m0row + 4);
  float acc[8] = {a0.x, a0.y, a0.z, a0.w, a1.x, a1.y, a1.z, a1.w};
  float stacc = 0.f;
#pragma unroll
  for (int k = 0; k < KK; ++k) {
    float e = es[k] * inv;
    const float* tv = token_val + ((size_t)b * SS + js[k]) * DD + dbase;
    float4 u0 = *reinterpret_cast<const float4*>(tv);
    float4 u1 = *reinterpret_cast<const float4*>(tv + 4);
    acc[0] += e * u0.x; acc[1] += e * u0.y; acc[2] += e * u0.z; acc[3] += e * u0.w;
    acc[4] += e * u1.x; acc[5] += e * u1.y; acc[6] += e * u1.z; acc[7] += e * u1.w;
    stacc += e * token_state[(size_t)b * SS + js[k]];
  }
  if (lane == 0) ms_w[row] = ms0[m] + stacc;
  float s1 = 0.f, s2 = 0.f;
#pragma unroll
  for (int c = 0; c < 8; ++c) { s1 += acc[c]; s2 += acc[c] * acc[c]; }
  s1 = wave_sum(s1);
  s2 = wave_sum(s2);
  float mean = s1 * (1.0f / DD);
  float var = s2 * (1.0f / DD) - mean * mean;
  float rs = rsqrtf(var + 1e-5f);
  float4 g0 = *reinterpret_cast<const float4*>(ln_g + dbase);
  float4 g1 = *reinterpret_cast<const float4*>(ln_g + dbase + 4);
  float4 b0v = *reinterpret_cast<const float4*>(ln_b + dbase);
  float4 b1v = *reinterpret_cast<const float4*>(ln_b + dbase + 4);
  float4 o0, o1;
  o0.x = (acc[0] - mean) * rs * g0.x + b0v.x;
  o0.y = (acc[1] - mean) * rs * g0.y + b0v.y;
  o0.z = (acc[2] - mean) * rs * g0.z + b0v.z;
  o0.w = (acc[3] - mean) * rs * g0.w + b0v.w;
  o1.x = (acc[4] - mean) * rs * g1.x + b1v.x;
  o1.y = (acc[5] - mean) * rs * g1.y + b1v.y;
  o1.z = (acc[6] - mean) * rs * g1.z + b1v.z;
  o1.w = (acc[7] - mean) * rs * g1.w + b1v.w;
  float* orow = mv1 + (size_t)row * DD + dbase;
  *reinterpret_cast<float4*>(orow) = o0;
  *reinterpret_cast<float4*>(orow + 4) = o1;
}

// ---------------------------------------------------------------------------
// One WAVE per (b,m): pscores[j] = pt1[row,:]·ps1T[b,:,j] (ms1 folded in);
// ballot-threshold top-16 -> edges -> gather mv1 -> residual -> LN -> out.
// ---------------------------------------------------------------------------
__global__ __launch_bounds__(256, 4) void k_prop(
    const float* __restrict__ pt1, const float* __restrict__ ps1T,
    const float* __restrict__ mv1, const float* __restrict__ ln_g,
    const float* __restrict__ ln_b, float* __restrict__ out) {
  int t = threadIdx.x;
  int wave = t >> 6, lane = t & 63;
  int row = blockIdx.x * 4 + wave;          // row = b*MM + m
  int b = row >> 8, m = row & 255;
  __shared__ int selj_sh[4][KK];
  __shared__ float selv_sh[4][KK];
  float ptval = pt1[(size_t)row * RR + lane];
  const float* pB = ps1T + (size_t)b * RR * MM + lane * 4;
  float sc[4] = {0.f, 0.f, 0.f, 0.f};
#pragma unroll 8
  for (int r = 0; r < RR; ++r) {
    float w = __shfl(ptval, r);
    float4 pv = *reinterpret_cast<const float4*>(pB + r * MM);
    sc[0] += w * pv.x; sc[1] += w * pv.y; sc[2] += w * pv.z; sc[3] += w * pv.w;
  }
  int jbase = lane * 4;
  unsigned au[4];
#pragma unroll
  for (int c = 0; c < 4; ++c) au[c] = __float_as_uint(sc[c]) & 0x7fffffffu;
  unsigned lo = 0u, hi = 0x7f800000u, thr = 0u;
  bool early = false;
  while (lo < hi) {
    unsigned mid = lo + ((hi - lo + 1u) >> 1);
    int cnt = 0;
#pragma unroll
    for (int c = 0; c < 4; ++c) cnt += __popcll(__ballot(au[c] >= mid));
    if (cnt == KK) { thr = mid; early = true; break; }
    if (cnt > KK) lo = mid; else hi = mid - 1u;
  }
  if (!early) thr = lo;
  unsigned long long ltmask = (1ull << lane) - 1ull;
  int s = 0;
  unsigned tiemask = 0u;
#pragma unroll
  for (int c = 0; c < 4; ++c) {
    bool sg = early ? (au[c] >= thr) : (au[c] > thr);
    unsigned long long mk = __ballot(sg);
    if (sg) {
      int slot = s + __popcll(mk & ltmask);
      selj_sh[wave][slot] = jbase + c;
      selv_sh[wave][slot] = sc[c];
    }
    s += __popcll(mk);
    if (!early && au[c] == thr) tiemask |= 1u << c;
  }
  int taken = s;
  while (taken < KK) {
    int myj = 0x7fffffff;
#pragma unroll
    for (int c = 0; c < 4; ++c)
      if ((tiemask >> c) & 1u) myj = min(myj, jbase + c);
    int wj = myj;
#pragma unroll
    for (int off = 32; off > 0; off >>= 1) wj = min(wj, __shfl_xor(wj, off));
    if (wj == 0x7fffffff) break;
    if (wj >= jbase && wj < jbase + 4) {
      tiemask &= ~(1u << (wj - jbase));
      selv_sh[wave][taken] = sc[wj - jbase];
      if (lane == (wj >> 2)) selj_sh[wave][taken] = wj;
    }
    ++taken;
  }
  int js[KK];
  float es[KK];
#pragma unroll
  for (int k = 0; k < KK; ++k) { js[k] = selj_sh[wave][k]; es[k] = selv_sh[wave][k]; }
  float mx = 0.f;
#pragma unroll
  for (int k = 0; k < KK; ++k) mx = fmaxf(mx, fabsf(es[k]));
  float ssum = 0.f;
#pragma unroll
  for (int k = 0; k < KK; ++k) {
    float ex = expf(fabsf(es[k]) - mx);
    ssum += ex;
    es[k] = sgnf(es[k]) * ex;
  }
  float inv = 1.f / ssum;
  int dbase = lane * 8;
  const float* mrow = mv1 + (size_t)row * DD + dbase;
  float4 a0 = *reinterpret_cast<const float4*>(mrow);
  float4 a1 = *reinterpret_cast<const float4*>(mrow + 4);
  float acc[8] = {a0.x, a0.y, a0.z, a0.w, a1.x, a1.y, a1.z, a1.w};
#pragma unroll
  for (int k = 0; k < KK; ++k) {
    float e = es[k] * inv;
    const float* pv = mv1 + ((size_t)b * MM + js[k]) * DD + dbase;
    float4 u0 = *reinterpret_cast<const float4*>(pv);
    float4 u1 = *reinterpret_cast<const float4*>(pv + 4);
    acc[0] += e * u0.x; acc[1] += e * u0.y; acc[2] += e * u0.z; acc[3] += e * u0.w;
    acc[4] += e * u1.x; acc[5] += e * u1.y; acc[6] += e * u1.z; acc[7] += e * u1.w;
  }
  float s1 = 0.f, s2 = 0.f;
#pragma unroll
  for (int c = 0; c < 8; ++c) { s1 += acc[c]; s2 += acc[c] * acc[c]; }
  s1 = wave_sum(s1);
  s2 = wave_sum(s2);
  float mean = s1 * (1.0f / DD);
  float var = s2 * (1.0f / DD) - mean * mean;
  float rs = rsqrtf(var + 1e-5f);
  float4 g0 = *reinterpret_cast<const float4*>(ln_g + dbase);
  float4 g1 = *reinterpret_cast<const float4*>(ln_g + dbase + 4);
  float4 b0v = *reinterpret_cast<const float4*>(ln_b + dbase);
  float4 b1v = *reinterpret_cast<const float4*>(ln_b + dbase + 4);
  float4 o0, o1;
  o0.x = (acc[0] - mean) * rs * g0.x + b0v.x;
  o0.y = (acc[1] - mean) * rs * g0.y + b0v.y;
  o0.z = (acc[2] - mean) * rs * g0.z + b0v.z;
  o0.w = (acc[3] - mean) * rs * g0.w + b0v.w;
  o1.x = (acc[4] - mean) * rs * g1.x + b1v.x;
  o1.y = (acc[5] - mean) * rs * g1.y + b1v.y;
  o1.z = (acc[6] - mean) * rs * g1.z + b1v.z;
  o1.w = (acc[7] - mean) * rs * g1.w + b1v.w;
  float* orow = out + (size_t)row * DD + dbase;
  *reinterpret_cast<float4*>(orow) = o0;
  *reinterpret_cast<float4*>(orow + 4) = o1;
}

extern "C" void kernel_launch(void* const* d_in, const int* in_sizes, int n_in,
                              void* d_out, int out_size, void* d_ws,
                              size_t ws_size, hipStream_t stream) {
  const float* token_val = (const float*)d_in[0];
  const float* token_state = (const float*)d_in[1];
  const float* init_state = (const float*)d_in[2];
  const float* init_val = (const float*)d_in[3];
  const float* rUs_w = (const float*)d_in[4];
  const float* rUs_b = (const float*)d_in[5];
  const float* rUt_w = (const float*)d_in[6];
  const float* rUt_b = (const float*)d_in[7];
  const float* r_w = (const float*)d_in[8];
  const float* pUs_w = (const float*)d_in[9];
  const float* pUs_b = (const float*)d_in[10];
  const float* pUt_w = (const float*)d_in[11];
  const float* pUt_b = (const float*)d_in[12];
  const float* p_w = (const float*)d_in[13];
  const float* ln_g = (const float*)d_in[14];
  const float* ln_b = (const float*)d_in[15];
  float* out = (float*)d_out;

  float* ws = (float*)d_ws;
  float* mv0 = ws;    ws += MM * DD;
  float* pt0 = ws;    ws += MM * RR;
  float* ms0 = ws;    ws += MM;
  float* ps = ws;     ws += (size_t)BB * SS * RR;
  float* scores = ws; ws += (size_t)BB * MM * SS;
  float* mv1 = ws;    ws += (size_t)BB * MM * DD;
  float* ms_w = ws;   ws += BB * MM;
  float* ms1 = ws;    ws += BB * MM;
  float* pt1 = ws;    ws += (size_t)BB * MM * RR;
  float* ps1T = ws;   ws += (size_t)BB * RR * MM;

  k_init<<<MM, 256, 0, stream>>>(init_val, ln_g, ln_b, rUt_w, rUt_b, r_w, mv0, pt0);
  k_state_softmax<<<1, 256, 0, stream>>>(init_state, ms0);
  k_gemm_skinny<<<(BB * SS) / 64, 256, 0, stream>>>(token_val, rUs_w, rUs_b, ps);
  dim3 gs(SS / 64, MM / 64, BB);
  k_scores<<<gs, 256, 0, stream>>>(pt0, ps, scores);
  k_write<<<(BB * MM) / 4, 256, 0, stream>>>(scores, token_val, token_state,
                                             mv0, ms0, ln_g, ln_b, mv1, ms_w);
  k_state_softmax<<<BB, 256, 0, stream>>>(ms_w, ms1);
  k_gemm_pair<<<128, 256, 0, stream>>>(mv1, pUt_w, pUt_b, p_w, pUs_w, pUs_b,
                                       ms1, pt1, ps1T);
  k_prop<<<(BB * MM) / 4, 256, 0, stream>>>(pt1, ps1T, mv1, ln_g, ln_b, out);
}